// Round 5
// baseline (337.665 us; speedup 1.0000x reference)
//
#include <hip/hip_runtime.h>
#include <stdint.h>

#define NB 8
#define NH 96
#define NW_ 96
#define NA 9
#define NANCH (NH * NW_ * NA)   // 82944
#define KPRE 4000
#define MAXOUT 2000
#define KEYCAP 4224             // >= KPRE + max expected cut-bucket size
#define WPR 64                  // mask row stride in u64 words (63 used + 1 pad)
#define NWORDS 63               // ceil(4000/64)

typedef unsigned long long u64;

// ---------------- Kernel 1: per-batch histogram of score bits ----------------
__global__ void k_hist(const float* __restrict__ score, unsigned* __restrict__ hist) {
    const int b = blockIdx.y;
    __shared__ unsigned h[4096];
    for (int i = threadIdx.x; i < 4096; i += blockDim.x) h[i] = 0u;
    __syncthreads();
    const float* s = score + (size_t)b * NANCH;
    int start = blockIdx.x * blockDim.x + threadIdx.x;
    int stride = gridDim.x * blockDim.x;
    for (int i = start; i < NANCH; i += stride) {
        float v = s[i];
        if (v > 0.5f) {
            unsigned bits = __float_as_uint(v);
            atomicAdd(&h[(bits >> 11) & 4095u], 1u);
        }
    }
    __syncthreads();
    for (int k = threadIdx.x; k < 4096; k += blockDim.x) {
        unsigned c = h[k];
        if (c) atomicAdd(&hist[b * 4096 + k], c);
    }
}

// ------- Kernel 2: one wave/batch suffix-scan -> starts, cut, P, M ------------
__global__ __launch_bounds__(64) void k_cut(unsigned* __restrict__ hist,
                                            unsigned* __restrict__ start,
                                            unsigned* __restrict__ meta) {
    const int b = blockIdx.x;
    const int lane = threadIdx.x;
    const int base = b * 4096 + lane * 64;
    unsigned v[64];
#pragma unroll
    for (int k = 0; k < 64; ++k) { v[k] = hist[base + k]; }
#pragma unroll
    for (int k = 0; k < 64; ++k) { hist[base + k] = 0u; }   // becomes bcnt
#pragma unroll
    for (int k = 62; k >= 0; --k) v[k] += v[k + 1];
    unsigned tot = v[0];
    unsigned incl = tot;
#pragma unroll
    for (int d = 1; d < 64; d <<= 1) {
        unsigned t = __shfl_down(incl, d);
        if (lane + d < 64) incl += t;
    }
    unsigned sfx_above = incl - tot;          // sum over lanes > lane
    unsigned total = __shfl(incl, 0);
#pragma unroll
    for (int k = 0; k < 63; ++k) start[base + k] = v[k + 1] + sfx_above;
    start[base + 63] = sfx_above;
    if (lane == 0) {
        unsigned P = total < KEYCAP ? total : KEYCAP;
        meta[b] = 0u;
        meta[8 + b] = P;
        meta[16 + b] = P < KPRE ? P : KPRE;
    }
#pragma unroll
    for (int k = 0; k < 64; ++k) {
        unsigned sfxk = v[k] + sfx_above;
        unsigned nxt = (k < 63) ? (v[k + 1] + sfx_above) : sfx_above;
        if (sfxk >= (unsigned)KPRE && nxt < (unsigned)KPRE) {
            unsigned P = sfxk < KEYCAP ? sfxk : KEYCAP;
            meta[b] = (unsigned)(lane * 64 + k);
            meta[8 + b] = P;
            meta[16 + b] = (unsigned)KPRE;
        }
    }
}

// ---------------- Kernel 3: bucketed scatter of candidate keys ---------------
__global__ void k_collect(const float* __restrict__ score, const unsigned* __restrict__ meta,
                          const unsigned* __restrict__ start, unsigned* __restrict__ bcnt,
                          u64* __restrict__ keys) {
    const int b = blockIdx.y;
    const unsigned cut = meta[b];
    const float* sc = score + (size_t)b * NANCH;
    int i0 = blockIdx.x * blockDim.x + threadIdx.x;
    int stride = gridDim.x * blockDim.x;
    for (int i = i0; i < NANCH; i += stride) {
        float v = sc[i];
        if (v > 0.5f) {
            unsigned bits = __float_as_uint(v);
            unsigned bucket = (bits >> 11) & 4095u;
            if (bucket >= cut) {
                unsigned pos = start[b * 4096 + bucket] + atomicAdd(&bcnt[b * 4096 + bucket], 1u);
                if (pos < (unsigned)KEYCAP)
                    keys[(size_t)b * KEYCAP + pos] =
                        ((u64)bits << 32) | (unsigned)(~(unsigned)i);
            }
        }
    }
}

// -------- Kernel 4: rank within bucket (exact sort position) + decode --------
__global__ void k_rank_decode(const u64* __restrict__ keys,
                              const unsigned* __restrict__ start,
                              const unsigned* __restrict__ meta,
                              const float* __restrict__ delta,
                              const float* __restrict__ anchors,
                              float* __restrict__ cand) {
#pragma clang fp contract(off)
    const int b = blockIdx.y;
    const int s = blockIdx.x * blockDim.x + threadIdx.x;
    const int P = (int)meta[8 + b];
    const int M = (int)meta[16 + b];
    if (s >= M && s < KPRE) {
        float4* c4 = (float4*)(cand + (size_t)b * KPRE * 4);
        c4[s] = make_float4(0.f, 0.f, 0.f, 0.f);
    }
    if (s >= P) return;
    const u64* kb = keys + (size_t)b * KEYCAP;
    u64 key = kb[s];
    unsigned bucket = (unsigned)(key >> 43) & 4095u;
    int base = (int)start[b * 4096 + bucket];
    int end = (bucket > 0) ? (int)start[b * 4096 + bucket - 1] : P;
    if (end > P) end = P;
    int rank = 0;
    for (int t = base; t < end; ++t) rank += (kb[t] > key) ? 1 : 0;
    int pos = base + rank;
    if (pos >= KPRE) return;
    int n = (int)(~(unsigned)(key & 0xFFFFFFFFull));
    float4 t4 = *(const float4*)(delta + ((size_t)b * NANCH + n) * 4);
    float4 a4 = *(const float4*)(anchors + (size_t)n * 4);
    float xa = (a4.x + a4.y) * 0.5f;
    float ya = (a4.z + a4.w) * 0.5f;
    float wa = a4.y - a4.x;
    float ha = a4.w - a4.z;
    float x = t4.x * wa + xa;
    float y = t4.y * ha + ya;
    float w = expf(t4.z) * wa;
    float h = expf(t4.w) * ha;
    float xmn = fminf(fmaxf(x - w * 0.5f, 0.f), 1.f);
    float xmx = fminf(fmaxf(x + w * 0.5f, 0.f), 1.f);
    float ymn = fminf(fmaxf(y - h * 0.5f, 0.f), 1.f);
    float ymx = fminf(fmaxf(y + h * 0.5f, 0.f), 1.f);
    float* o = cand + ((size_t)b * KPRE + pos) * 4;
    o[0] = xmn; o[1] = xmx; o[2] = ymn; o[3] = ymx;
}

// ---------------- Kernel 5: upper-triangle suppression bit matrix ------------
__global__ void k_mask(const float* __restrict__ cand, u64* __restrict__ mask) {
#pragma clang fp contract(off)
    const int b = blockIdx.y;
    const int c = blockIdx.x;       // row chunk of 64
    __shared__ float4 sb4[KPRE];    // 64 KB
    __shared__ float sar[KPRE];     // 16 KB areas
    {
        const float4* c4 = (const float4*)(cand + (size_t)b * KPRE * 4);
        for (int k = threadIdx.x; k < KPRE; k += blockDim.x) {
            float4 v = c4[k];
            sb4[k] = v;
            sar[k] = (v.y - v.x) * (v.w - v.z);
        }
    }
    __syncthreads();
    for (int task = threadIdx.x; task < 64 * NWORDS; task += blockDim.x) {
        const int ri = task & 63;   // lane -> row, word uniform per wave
        const int w = task >> 6;
        const int i = (c << 6) + ri;
        if (i >= KPRE) continue;
        u64 bits = 0ull;
        if (w >= c) {
            float4 bi = sb4[i];
            float ai = sar[i];
            const int j0 = w << 6;
            const int jlim = (j0 + 64 <= KPRE) ? 64 : (KPRE - j0);
            int jj = (w == c) ? ri + 1 : 0;
            for (; jj < jlim; ++jj) {
                float4 bj = sb4[j0 + jj];
                float iw = fminf(bi.y, bj.y) - fmaxf(bi.x, bj.x);
                iw = fmaxf(iw, 0.0f);
                float ih = fminf(bi.w, bj.w) - fmaxf(bi.z, bj.z);
                ih = fmaxf(ih, 0.0f);
                float inter = iw * ih;
                float aj = sar[j0 + jj];
                if (inter > 0.69f * fmaxf(ai, aj)) {
                    float uni = ai + aj - inter;
                    float iou = inter / fmaxf(uni, 1e-8f);
                    if (iou > 0.7f) bits |= (1ull << jj);
                }
            }
        }
        mask[((size_t)b * KPRE + i) * WPR + w] = bits;
    }
}

// ---- Kernel 6: greedy NMS — pure scalar scan chain, eager column loads ------
__device__ __forceinline__ void gl_lds16(const void* g, void* l) {
    __builtin_amdgcn_global_load_lds(
        (const __attribute__((address_space(1))) void*)g,
        (__attribute__((address_space(3))) void*)l, 16, 0, 0);
}
__device__ __forceinline__ u64 readlane64(u64 v, int l) {
    unsigned lo = (unsigned)__builtin_amdgcn_readlane((int)(unsigned)v, l);
    unsigned hi = (unsigned)__builtin_amdgcn_readlane((int)(unsigned)(v >> 32), l);
    return ((u64)hi << 32) | lo;
}
__device__ __forceinline__ u64 rfl64(u64 v) {
    unsigned lo = (unsigned)__builtin_amdgcn_readfirstlane((int)(unsigned)v);
    unsigned hi = (unsigned)__builtin_amdgcn_readfirstlane((int)(unsigned)(v >> 32));
    return ((u64)hi << 32) | lo;
}
#define WAITVM0   asm volatile("s_waitcnt vmcnt(0)" ::: "memory")
#define WAITLGKM0 asm volatile("s_waitcnt lgkmcnt(0)" ::: "memory")

__global__ __launch_bounds__(64) void k_nms(const u64* __restrict__ mask,
                                            const float* __restrict__ cand,
                                            const unsigned* __restrict__ meta,
                                            float* __restrict__ out) {
    const int b = blockIdx.x;
    const int lane = threadIdx.x;
    const int M = (int)meta[16 + b];
    const u64* mrow = mask + (size_t)b * KPRE * WPR;
    __shared__ u64 buf[3 * 64 * 64];   // 96 KB triple buffer (fold staging only)
    __shared__ int sel[MAXOUT];        // 8 KB
    __shared__ u64 amlist_s[64];
    amlist_s[lane] = 0ull;

    u64 rem_dist = 0ull;   // lane l: OR of word l over accepts of chunks folded so far (lag 1)
    int cnt = 0;
    const int nchunks = (M + 63) >> 6;

    auto prefetch = [&](int cc) {      // stage chunk cc's 64 rows for the lag-1 fold
        if (cc >= nchunks) return;
        const int j0 = cc << 6;
        const int nrows = (KPRE - j0) < 64 ? (KPRE - j0) : 64;   // even
        const int ninstr = nrows >> 1;                            // 1KB each
        const char* gsrc = (const char*)(mrow + (size_t)j0 * WPR) + lane * 16;
        char* ldst = (char*)buf + (size_t)(cc % 3) * 32768;
#pragma unroll 4
        for (int k = 0; k < ninstr; ++k)
            gl_lds16(gsrc + k * 1024, ldst + k * 1024);
    };

    if (nchunks > 0) {
        prefetch(0);
        // prologue: diag block of chunk 0 (word 0 of rows 0..63), per-lane column load
        u64 vdiag = mrow[(size_t)lane * WPR + 0];
        u64 remw = 0ull;       // rem word for current chunk (uniform)
        u64 am_prev = 0ull;

        for (int c = 0; c < nchunks; ++c) {
            WAITLGKM0;                       // fold(c-2)'s LDS reads drained (no stall)
            prefetch(c + 1);                 // 32 gl_lds, consumed by fold in chunk c+2
            const int j0 = c << 6;
            u64 vdiag_nx = 0ull, vfix = 0ull;
            if (c + 1 < nchunks) {
                int rd = j0 + 64 + lane; if (rd >= KPRE) rd = KPRE - 1;
                vdiag_nx = mrow[(size_t)rd * WPR + (c + 1)];   // diag of chunk c+1
                int rf = j0 + lane; if (rf >= KPRE) rf = KPRE - 1;
                vfix = mrow[(size_t)rf * WPR + (c + 1)];       // word c+1 of chunk c rows
            }

            // ---- serial scan of chunk c (SALU + readlane only) ----
            int nrow = M - j0;
            u64 live = ~remw;
            if (nrow < 64) live &= (1ull << nrow) - 1ull;
            u64 am = 0ull;
            while (live && cnt < MAXOUT) {
                int jj = __builtin_amdgcn_readfirstlane(__builtin_ctzll(live));
                u64 dw = readlane64(vdiag, jj);
                ++cnt;
                am |= (1ull << jj);
                live &= ~(dw | (1ull << jj));
            }
            if (lane == 0) amlist_s[c] = am;
            if (cnt >= MAXOUT) break;

            // ---- lag-1 fold: chunk c-1's accepted rows -> rem_dist ----
            if (c > 0 && am_prev) {
                const u64* bufp = buf + (size_t)((c - 1) % 3) * 4096;
                u64 a0 = 0, a1 = 0, a2 = 0, a3 = 0;
#pragma unroll
                for (int k = 0; k < 64; k += 4) {
                    u64 m0 = 0ull - ((am_prev >> (k + 0)) & 1ull);
                    u64 m1 = 0ull - ((am_prev >> (k + 1)) & 1ull);
                    u64 m2 = 0ull - ((am_prev >> (k + 2)) & 1ull);
                    u64 m3 = 0ull - ((am_prev >> (k + 3)) & 1ull);
                    a0 |= bufp[((k + 0) << 6) + lane] & m0;
                    a1 |= bufp[((k + 1) << 6) + lane] & m1;
                    a2 |= bufp[((k + 2) << 6) + lane] & m2;
                    a3 |= bufp[((k + 3) << 6) + lane] & m3;
                }
                rem_dist |= (a0 | a1) | (a2 | a3);
            }

            WAITVM0;     // vdiag_nx/vfix/gl_lds issued >=1 scan ago -> no stall expected
            WAITLGKM0;   // fold reads drained (~issue+120cy, mostly overlapped)

            if (c + 1 < nchunks) {
                // rem word c+1 = folds(0..c-1) | chunk-c accepts' word c+1
                u64 contrib = vfix & (0ull - ((am >> lane) & 1ull));
#pragma unroll
                for (int d = 1; d < 64; d <<= 1) contrib |= __shfl_xor(contrib, d);
                remw = readlane64(rem_dist, c + 1) | rfl64(contrib);
            }
            vdiag = vdiag_nx;
            am_prev = am;
        }
        WAITVM0;   // in-flight gl_lds must not outlive LDS reuse / wave exit
    }

    __syncthreads();
    // expand amlist -> sel (wave-parallel, order-preserving)
    u64 myam = amlist_s[lane];
    int inc = __builtin_popcountll(myam);
    int scan = inc;
#pragma unroll
    for (int d = 1; d < 64; d <<= 1) {
        int t = __shfl_up(scan, d);
        if (lane >= d) scan += t;
    }
    int pos = scan - inc;
    while (myam) {
        int r = __builtin_ctzll(myam);
        myam &= myam - 1;
        sel[pos++] = (lane << 6) + r;
    }
    __syncthreads();

    const float4* c4 = (const float4*)(cand + (size_t)b * KPRE * 4);
    float4* o4 = (float4*)(out + (size_t)b * MAXOUT * 4);
    for (int r = lane; r < MAXOUT; r += 64) {
        float4 v = make_float4(0.0f, 0.0f, 0.0f, 0.0f);
        if (r < cnt) v = c4[sel[r]];
        o4[r] = v;
    }
}

// ---------------- launch ------------------------------------------------------
extern "C" void kernel_launch(void* const* d_in, const int* in_sizes, int n_in,
                              void* d_out, int out_size, void* d_ws, size_t ws_size,
                              hipStream_t stream) {
    const float* score   = (const float*)d_in[0];
    const float* delta   = (const float*)d_in[1];
    const float* anchors = (const float*)d_in[2];
    float* out = (float*)d_out;

    uint8_t* w8 = (uint8_t*)d_ws;
    unsigned* hist = (unsigned*)(w8 + 0);                 // 8 x 4096 u32 (then bcnt)
    unsigned* start = (unsigned*)(w8 + 131072);           // 8 x 4096 u32
    unsigned* meta = (unsigned*)(w8 + 262144);            // cut[8] | P[8] | M[8]
    u64* keys = (u64*)(w8 + 262272);                      // 8 x 4224 u64
    float* cand = (float*)(w8 + 532608);                  // 8 x 4000 x 4 f32
    u64* mask = (u64*)(w8 + 1044608);                     // 8 x 4000 x 64 u64

    hipMemsetAsync(hist, 0, 8 * 4096 * sizeof(unsigned), stream);
    k_hist<<<dim3(16, NB), 256, 0, stream>>>(score, hist);
    k_cut<<<NB, 64, 0, stream>>>(hist, start, meta);
    k_collect<<<dim3(32, NB), 256, 0, stream>>>(score, meta, start, hist /*bcnt*/, keys);
    k_rank_decode<<<dim3((KEYCAP + 255) / 256, NB), 256, 0, stream>>>(keys, start, meta,
                                                                      delta, anchors, cand);
    k_mask<<<dim3((KPRE + 63) / 64, NB), 256, 0, stream>>>(cand, mask);
    k_nms<<<NB, 64, 0, stream>>>(mask, cand, meta, out);
}

// Round 6
// 337.575 us; speedup vs baseline: 1.0003x; 1.0003x over previous
//
#include <hip/hip_runtime.h>
#include <stdint.h>

#define NB 8
#define NH 96
#define NW_ 96
#define NA 9
#define NANCH (NH * NW_ * NA)   // 82944
#define KPRE 4000
#define MAXOUT 2000
#define KEYCAP 4224             // >= KPRE + max expected cut-bucket size
#define WPR 64                  // mask row stride in u64 words (63 used + 1 pad)
#define NWORDS 63               // ceil(4000/64)

typedef unsigned long long u64;

// ---------------- Kernel 1: per-batch histogram of score bits ----------------
__global__ void k_hist(const float* __restrict__ score, unsigned* __restrict__ hist) {
    const int b = blockIdx.y;
    __shared__ unsigned h[4096];
    for (int i = threadIdx.x; i < 4096; i += blockDim.x) h[i] = 0u;
    __syncthreads();
    const float* s = score + (size_t)b * NANCH;
    int start = blockIdx.x * blockDim.x + threadIdx.x;
    int stride = gridDim.x * blockDim.x;
    for (int i = start; i < NANCH; i += stride) {
        float v = s[i];
        if (v > 0.5f) {
            unsigned bits = __float_as_uint(v);
            atomicAdd(&h[(bits >> 11) & 4095u], 1u);
        }
    }
    __syncthreads();
    for (int k = threadIdx.x; k < 4096; k += blockDim.x) {
        unsigned c = h[k];
        if (c) atomicAdd(&hist[b * 4096 + k], c);
    }
}

// ------- Kernel 2: one wave/batch suffix-scan -> starts, cut, P, M ------------
__global__ __launch_bounds__(64) void k_cut(unsigned* __restrict__ hist,
                                            unsigned* __restrict__ start,
                                            unsigned* __restrict__ meta) {
    const int b = blockIdx.x;
    const int lane = threadIdx.x;
    const int base = b * 4096 + lane * 64;
    unsigned v[64];
#pragma unroll
    for (int k = 0; k < 64; ++k) { v[k] = hist[base + k]; }
#pragma unroll
    for (int k = 0; k < 64; ++k) { hist[base + k] = 0u; }   // becomes bcnt
#pragma unroll
    for (int k = 62; k >= 0; --k) v[k] += v[k + 1];
    unsigned tot = v[0];
    unsigned incl = tot;
#pragma unroll
    for (int d = 1; d < 64; d <<= 1) {
        unsigned t = __shfl_down(incl, d);
        if (lane + d < 64) incl += t;
    }
    unsigned sfx_above = incl - tot;          // sum over lanes > lane
    unsigned total = __shfl(incl, 0);
#pragma unroll
    for (int k = 0; k < 63; ++k) start[base + k] = v[k + 1] + sfx_above;
    start[base + 63] = sfx_above;
    if (lane == 0) {
        unsigned P = total < KEYCAP ? total : KEYCAP;
        meta[b] = 0u;
        meta[8 + b] = P;
        meta[16 + b] = P < KPRE ? P : KPRE;
    }
#pragma unroll
    for (int k = 0; k < 64; ++k) {
        unsigned sfxk = v[k] + sfx_above;
        unsigned nxt = (k < 63) ? (v[k + 1] + sfx_above) : sfx_above;
        if (sfxk >= (unsigned)KPRE && nxt < (unsigned)KPRE) {
            unsigned P = sfxk < KEYCAP ? sfxk : KEYCAP;
            meta[b] = (unsigned)(lane * 64 + k);
            meta[8 + b] = P;
            meta[16 + b] = (unsigned)KPRE;
        }
    }
}

// ---------------- Kernel 3: bucketed scatter of candidate keys ---------------
__global__ void k_collect(const float* __restrict__ score, const unsigned* __restrict__ meta,
                          const unsigned* __restrict__ start, unsigned* __restrict__ bcnt,
                          u64* __restrict__ keys) {
    const int b = blockIdx.y;
    const unsigned cut = meta[b];
    const float* sc = score + (size_t)b * NANCH;
    int i0 = blockIdx.x * blockDim.x + threadIdx.x;
    int stride = gridDim.x * blockDim.x;
    for (int i = i0; i < NANCH; i += stride) {
        float v = sc[i];
        if (v > 0.5f) {
            unsigned bits = __float_as_uint(v);
            unsigned bucket = (bits >> 11) & 4095u;
            if (bucket >= cut) {
                unsigned pos = start[b * 4096 + bucket] + atomicAdd(&bcnt[b * 4096 + bucket], 1u);
                if (pos < (unsigned)KEYCAP)
                    keys[(size_t)b * KEYCAP + pos] =
                        ((u64)bits << 32) | (unsigned)(~(unsigned)i);
            }
        }
    }
}

// -------- Kernel 4: rank within bucket (exact sort position) + decode --------
__global__ void k_rank_decode(const u64* __restrict__ keys,
                              const unsigned* __restrict__ start,
                              const unsigned* __restrict__ meta,
                              const float* __restrict__ delta,
                              const float* __restrict__ anchors,
                              float* __restrict__ cand) {
#pragma clang fp contract(off)
    const int b = blockIdx.y;
    const int s = blockIdx.x * blockDim.x + threadIdx.x;
    const int P = (int)meta[8 + b];
    const int M = (int)meta[16 + b];
    if (s >= M && s < KPRE) {
        float4* c4 = (float4*)(cand + (size_t)b * KPRE * 4);
        c4[s] = make_float4(0.f, 0.f, 0.f, 0.f);
    }
    if (s >= P) return;
    const u64* kb = keys + (size_t)b * KEYCAP;
    u64 key = kb[s];
    unsigned bucket = (unsigned)(key >> 43) & 4095u;
    int base = (int)start[b * 4096 + bucket];
    int end = (bucket > 0) ? (int)start[b * 4096 + bucket - 1] : P;
    if (end > P) end = P;
    int rank = 0;
    for (int t = base; t < end; ++t) rank += (kb[t] > key) ? 1 : 0;
    int pos = base + rank;
    if (pos >= KPRE) return;
    int n = (int)(~(unsigned)(key & 0xFFFFFFFFull));
    float4 t4 = *(const float4*)(delta + ((size_t)b * NANCH + n) * 4);
    float4 a4 = *(const float4*)(anchors + (size_t)n * 4);
    float xa = (a4.x + a4.y) * 0.5f;
    float ya = (a4.z + a4.w) * 0.5f;
    float wa = a4.y - a4.x;
    float ha = a4.w - a4.z;
    float x = t4.x * wa + xa;
    float y = t4.y * ha + ya;
    float w = expf(t4.z) * wa;
    float h = expf(t4.w) * ha;
    float xmn = fminf(fmaxf(x - w * 0.5f, 0.f), 1.f);
    float xmx = fminf(fmaxf(x + w * 0.5f, 0.f), 1.f);
    float ymn = fminf(fmaxf(y - h * 0.5f, 0.f), 1.f);
    float ymx = fminf(fmaxf(y + h * 0.5f, 0.f), 1.f);
    float* o = cand + ((size_t)b * KPRE + pos) * 4;
    o[0] = xmn; o[1] = xmx; o[2] = ymn; o[3] = ymx;
}

// ------ Kernel 5: suppression bit matrix + compact diag-block table ----------
__global__ void k_mask(const float* __restrict__ cand, u64* __restrict__ mask,
                       u64* __restrict__ diagc) {
#pragma clang fp contract(off)
    const int b = blockIdx.y;
    const int c = blockIdx.x;       // row chunk of 64
    __shared__ float4 sb4[KPRE];    // 64 KB
    __shared__ float sar[KPRE];     // 16 KB areas
    {
        const float4* c4 = (const float4*)(cand + (size_t)b * KPRE * 4);
        for (int k = threadIdx.x; k < KPRE; k += blockDim.x) {
            float4 v = c4[k];
            sb4[k] = v;
            sar[k] = (v.y - v.x) * (v.w - v.z);
        }
    }
    __syncthreads();
    for (int task = threadIdx.x; task < 64 * NWORDS; task += blockDim.x) {
        const int ri = task & 63;   // lane -> row, word uniform per wave
        const int w = task >> 6;
        const int i = (c << 6) + ri;
        if (i >= KPRE) continue;
        u64 bits = 0ull;
        if (w >= c) {
            float4 bi = sb4[i];
            float ai = sar[i];
            const int j0 = w << 6;
            const int jlim = (j0 + 64 <= KPRE) ? 64 : (KPRE - j0);
            int jj = (w == c) ? ri + 1 : 0;
            for (; jj < jlim; ++jj) {
                float4 bj = sb4[j0 + jj];
                float iw = fminf(bi.y, bj.y) - fmaxf(bi.x, bj.x);
                iw = fmaxf(iw, 0.0f);
                float ih = fminf(bi.w, bj.w) - fmaxf(bi.z, bj.z);
                ih = fmaxf(ih, 0.0f);
                float inter = iw * ih;
                float aj = sar[j0 + jj];
                if (inter > 0.69f * fmaxf(ai, aj)) {
                    float uni = ai + aj - inter;
                    float iou = inter / fmaxf(uni, 1e-8f);
                    if (iou > 0.7f) bits |= (1ull << jj);
                }
            }
        }
        mask[((size_t)b * KPRE + i) * WPR + w] = bits;
        if (w == c) diagc[((size_t)b << 12) + (size_t)i] = bits;  // compact diag
    }
}

// ---- Kernel 6: greedy NMS — lean chunks, LDS diag table, counted vmcnt ------
__device__ __forceinline__ void gl_lds16(const void* g, void* l) {
    __builtin_amdgcn_global_load_lds(
        (const __attribute__((address_space(1))) void*)g,
        (__attribute__((address_space(3))) void*)l, 16, 0, 0);
}
__device__ __forceinline__ u64 readlane64(u64 v, int l) {
    unsigned lo = (unsigned)__builtin_amdgcn_readlane((int)(unsigned)v, l);
    unsigned hi = (unsigned)__builtin_amdgcn_readlane((int)(unsigned)(v >> 32), l);
    return ((u64)hi << 32) | lo;
}
#define WAITVM0   asm volatile("s_waitcnt vmcnt(0)" ::: "memory")
#define WAITVM16  asm volatile("s_waitcnt vmcnt(16)" ::: "memory")
#define WAITVM32  asm volatile("s_waitcnt vmcnt(32)" ::: "memory")
#define WAITLGKM0 asm volatile("s_waitcnt lgkmcnt(0)" ::: "memory")
#define SCHEDBAR  __builtin_amdgcn_sched_barrier(0)

__global__ __launch_bounds__(64) void k_nms(const u64* __restrict__ mask,
                                            const u64* __restrict__ diagc,
                                            const float* __restrict__ cand,
                                            const unsigned* __restrict__ meta,
                                            float* __restrict__ out) {
    const int b = blockIdx.x;
    const int lane = threadIdx.x;
    const int M = (int)meta[16 + b];
    const u64* mrow = mask + (size_t)b * KPRE * WPR;
    __shared__ u64 buf[3 * 4096];     // 96 KB triple buffer (row staging for fold)
    __shared__ u64 diag_lds[4096];    // 32 KB: all chunks' diagonal blocks
    __shared__ int sel[MAXOUT];       // 8 KB
    __shared__ u64 amlist_s[64];
    amlist_s[lane] = 0ull;

    u64 rem = 0ull;                   // lane l owns suppression word l
    int cnt = 0;
    const int nchunks = (M + 63) >> 6;

    auto pf_n = [&](int cc) -> int {   // gl_lds instruction count for chunk cc
        if (cc >= nchunks) return 0;
        int nrows = KPRE - (cc << 6); if (nrows > 64) nrows = 64;
        return nrows >> 1;             // 1 KB (2 rows) per instruction
    };
    auto prefetch = [&](int cc) {
        int n = pf_n(cc);
        if (!n) return;
        const char* gsrc = (const char*)(mrow + ((size_t)(cc << 6)) * WPR) + lane * 16;
        char* ldst = (char*)buf + (size_t)(cc % 3) * 32768;
        for (int k = 0; k < n; ++k) gl_lds16(gsrc + k * 1024, ldst + k * 1024);
    };
    auto waitpend = [&](int n) {
        if (n == 32) { WAITVM32; } else if (n == 16) { WAITVM16; } else { WAITVM0; }
    };

    if (nchunks > 0) {
        // prologue: stage diag table (32 KB contiguous) + first two row-chunks
        {
            const char* dsrc = (const char*)(diagc + ((size_t)b << 12)) + lane * 16;
            for (int k = 0; k < 32; ++k) gl_lds16(dsrc + k * 1024, (char*)diag_lds + k * 1024);
        }
        prefetch(0);
        prefetch(1);
        waitpend(pf_n(1));            // diag table + pf(0) retired (in-order vmcnt)
        u64 vdiag = diag_lds[lane];   // chunk 0 diag, conflict-free
        WAITLGKM0; SCHEDBAR;

        for (int c = 0; c < nchunks; ++c) {
            const int j0 = c << 6;
            u64 cur = readlane64(rem, c);
            int nrow = M - j0;
            u64 live = ~cur;
            if (nrow < 64) live &= (1ull << nrow) - 1ull;

            // ---- serial scan (SALU + v_readlane only; no memory in chain) ----
            u64 am = 0ull;
            while (live && cnt < MAXOUT) {
                int jj = __builtin_amdgcn_readfirstlane(__builtin_ctzll(live));
                u64 dw = readlane64(vdiag, jj);
                ++cnt;
                am |= (1ull << jj);
                live &= ~(dw | (1ull << jj));
            }
            if (lane == 0) amlist_s[c] = am;
            if (cnt >= MAXOUT || c + 1 >= nchunks) break;

            waitpend(pf_n(c + 1));    // ensure pf(c) fully in LDS; pf(c+1) stays in flight
            SCHEDBAR;
            // ---- lag-0 fold: chunk c accepts -> rem (4 independent accumulators) ----
            if (am) {
                const u64* bufc = buf + (size_t)(c % 3) * 4096;
                u64 a0 = 0, a1 = 0, a2 = 0, a3 = 0;
#pragma unroll
                for (int k = 0; k < 64; k += 4) {
                    u64 m0 = 0ull - ((am >> (k + 0)) & 1ull);
                    u64 m1 = 0ull - ((am >> (k + 1)) & 1ull);
                    u64 m2 = 0ull - ((am >> (k + 2)) & 1ull);
                    u64 m3 = 0ull - ((am >> (k + 3)) & 1ull);
                    a0 |= bufc[((k + 0) << 6) + lane] & m0;
                    a1 |= bufc[((k + 1) << 6) + lane] & m1;
                    a2 |= bufc[((k + 2) << 6) + lane] & m2;
                    a3 |= bufc[((k + 3) << 6) + lane] & m3;
                }
                rem |= (a0 | a1) | (a2 | a3);
            }
            prefetch(c + 2);                            // consumed 2 chunks later
            vdiag = diag_lds[((c + 1) << 6) + lane];    // next chunk's diag
            WAITLGKM0; SCHEDBAR;
        }
        WAITVM0;   // in-flight gl_lds must not outlive LDS reuse / wave exit
    }

    __syncthreads();
    // expand amlist -> sel (wave-parallel, order-preserving)
    u64 myam = amlist_s[lane];
    int inc = __builtin_popcountll(myam);
    int scan = inc;
#pragma unroll
    for (int d = 1; d < 64; d <<= 1) {
        int t = __shfl_up(scan, d);
        if (lane >= d) scan += t;
    }
    int pos = scan - inc;
    while (myam) {
        int r = __builtin_ctzll(myam);
        myam &= myam - 1;
        sel[pos++] = (lane << 6) + r;
    }
    __syncthreads();

    const float4* c4 = (const float4*)(cand + (size_t)b * KPRE * 4);
    float4* o4 = (float4*)(out + (size_t)b * MAXOUT * 4);
    for (int r = lane; r < MAXOUT; r += 64) {
        float4 v = make_float4(0.0f, 0.0f, 0.0f, 0.0f);
        if (r < cnt) v = c4[sel[r]];
        o4[r] = v;
    }
}

// ---------------- launch ------------------------------------------------------
extern "C" void kernel_launch(void* const* d_in, const int* in_sizes, int n_in,
                              void* d_out, int out_size, void* d_ws, size_t ws_size,
                              hipStream_t stream) {
    const float* score   = (const float*)d_in[0];
    const float* delta   = (const float*)d_in[1];
    const float* anchors = (const float*)d_in[2];
    float* out = (float*)d_out;

    uint8_t* w8 = (uint8_t*)d_ws;
    unsigned* hist = (unsigned*)(w8 + 0);                 // 8 x 4096 u32 (then bcnt)
    unsigned* start = (unsigned*)(w8 + 131072);           // 8 x 4096 u32
    unsigned* meta = (unsigned*)(w8 + 262144);            // cut[8] | P[8] | M[8]
    u64* keys = (u64*)(w8 + 262272);                      // 8 x 4224 u64
    float* cand = (float*)(w8 + 532608);                  // 8 x 4000 x 4 f32
    u64* mask = (u64*)(w8 + 1044608);                     // 8 x 4000 x 64 u64
    // diagc reuses the keys region (dead after k_rank_decode): 8 x 4096 u64 = 256 KB <= 270 KB
    u64* diagc = keys;

    hipMemsetAsync(hist, 0, 8 * 4096 * sizeof(unsigned), stream);
    k_hist<<<dim3(16, NB), 256, 0, stream>>>(score, hist);
    k_cut<<<NB, 64, 0, stream>>>(hist, start, meta);
    k_collect<<<dim3(32, NB), 256, 0, stream>>>(score, meta, start, hist /*bcnt*/, keys);
    k_rank_decode<<<dim3((KEYCAP + 255) / 256, NB), 256, 0, stream>>>(keys, start, meta,
                                                                      delta, anchors, cand);
    k_mask<<<dim3((KPRE + 63) / 64, NB), 256, 0, stream>>>(cand, mask, diagc);
    k_nms<<<NB, 64, 0, stream>>>(mask, diagc, cand, meta, out);
}

// Round 7
// 263.980 us; speedup vs baseline: 1.2791x; 1.2788x over previous
//
#include <hip/hip_runtime.h>
#include <stdint.h>

#define NB 8
#define NH 96
#define NW_ 96
#define NA 9
#define NANCH (NH * NW_ * NA)   // 82944
#define KPRE 4000
#define MAXOUT 2000
#define KEYCAP 4224             // >= KPRE + max expected cut-bucket size
#define WPR 64                  // mask row stride in u64 words (63 used + 1 pad)
#define NWORDS 63               // ceil(4000/64)

typedef unsigned long long u64;

// ===== Kernel 1: fused front-end (hist + scan + cut + collect + rank + decode)
__global__ __launch_bounds__(1024) void k_front(const float* __restrict__ score,
                                                const float* __restrict__ delta,
                                                const float* __restrict__ anchors,
                                                float* __restrict__ cand,
                                                unsigned* __restrict__ meta) {
#pragma clang fp contract(off)
    const int b = blockIdx.x;
    const int tid = threadIdx.x;
    const int lane = tid & 63, wid = tid >> 6;
    __shared__ unsigned h[4096];       // 16 KB histogram
    __shared__ unsigned sstart[4096];  // 16 KB bucket start offsets
    __shared__ unsigned bc[4096];      // 16 KB bucket counters
    __shared__ u64 keysl[KEYCAP];      // 33.8 KB candidate keys
    __shared__ unsigned wsum[16], wabove[16];
    __shared__ unsigned s_cut, s_P, s_M;

    for (int k = tid; k < 4096; k += 1024) { h[k] = 0u; bc[k] = 0u; }
    __syncthreads();

    const float* sc = score + (size_t)b * NANCH;
    for (int i = tid; i < NANCH; i += 1024) {
        float v = sc[i];
        if (v > 0.5f) atomicAdd(&h[(__float_as_uint(v) >> 11) & 4095u], 1u);
    }
    __syncthreads();

    // suffix scan: thread t owns buckets [4t, 4t+4)
    unsigned l0 = h[tid * 4 + 0], l1 = h[tid * 4 + 1], l2 = h[tid * 4 + 2], l3 = h[tid * 4 + 3];
    unsigned s3 = l3, s2 = l2 + s3, s1 = l1 + s2, s0 = l0 + s1;
    unsigned incl = s0;
#pragma unroll
    for (int d = 1; d < 64; d <<= 1) {
        unsigned t = __shfl_down(incl, d);
        if (lane + d < 64) incl += t;
    }
    if (lane == 0) wsum[wid] = incl;
    __syncthreads();
    if (tid < 16) {
        unsigned a = 0;
        for (int w = tid + 1; w < 16; ++w) a += wsum[w];
        wabove[tid] = a;
    }
    __syncthreads();
    unsigned ta = (incl - s0) + wabove[wid];   // suffix strictly above this thread's buckets
    unsigned f0 = s0 + ta, f1 = s1 + ta, f2 = s2 + ta, f3 = s3 + ta, f4 = ta;
    sstart[tid * 4 + 0] = f1; sstart[tid * 4 + 1] = f2;
    sstart[tid * 4 + 2] = f3; sstart[tid * 4 + 3] = f4;
    if (tid == 0) {
        unsigned total = f0;
        unsigned P = total < KEYCAP ? total : KEYCAP;
        s_cut = 0u; s_P = P; s_M = P < KPRE ? P : KPRE;
    }
    __syncthreads();
    {
        unsigned fa[5] = {f0, f1, f2, f3, f4};
#pragma unroll
        for (int k = 0; k < 4; ++k) {
            if (fa[k] >= (unsigned)KPRE && fa[k + 1] < (unsigned)KPRE) {
                unsigned P = fa[k] < KEYCAP ? fa[k] : KEYCAP;
                s_cut = (unsigned)(tid * 4 + k); s_P = P; s_M = (unsigned)KPRE;
            }
        }
    }
    __syncthreads();
    const unsigned cut = s_cut; const int P = (int)s_P; const int M = (int)s_M;
    if (tid == 0) meta[16 + b] = (unsigned)M;

    // collect into LDS key buffer (bucketed scatter)
    for (int i = tid; i < NANCH; i += 1024) {
        float v = sc[i];
        if (v > 0.5f) {
            unsigned bits = __float_as_uint(v);
            unsigned bucket = (bits >> 11) & 4095u;
            if (bucket >= cut) {
                unsigned pos = sstart[bucket] + atomicAdd(&bc[bucket], 1u);
                if (pos < (unsigned)KEYCAP)
                    keysl[pos] = ((u64)bits << 32) | (unsigned)(~(unsigned)i);
            }
        }
    }
    __syncthreads();

    // rank within bucket -> exact sorted position; decode box there
    for (int s = tid; s < KEYCAP; s += 1024) {
        if (s >= M && s < KPRE) {
            float4* c4 = (float4*)(cand + (size_t)b * KPRE * 4);
            c4[s] = make_float4(0.f, 0.f, 0.f, 0.f);
        }
        if (s < P) {
            u64 key = keysl[s];
            unsigned bucket = (unsigned)(key >> 43) & 4095u;
            int base = (int)sstart[bucket];
            int end = (bucket > 0) ? (int)sstart[bucket - 1] : P;
            if (end > P) end = P;
            int rank = 0;
            for (int t = base; t < end; ++t) rank += (keysl[t] > key) ? 1 : 0;
            int pos = base + rank;
            if (pos < KPRE) {
                int n = (int)(~(unsigned)(key & 0xFFFFFFFFull));
                float4 t4 = *(const float4*)(delta + ((size_t)b * NANCH + n) * 4);
                float4 a4 = *(const float4*)(anchors + (size_t)n * 4);
                float xa = (a4.x + a4.y) * 0.5f;
                float ya = (a4.z + a4.w) * 0.5f;
                float wa = a4.y - a4.x;
                float ha = a4.w - a4.z;
                float x = t4.x * wa + xa;
                float y = t4.y * ha + ya;
                float w = expf(t4.z) * wa;
                float hh = expf(t4.w) * ha;
                float xmn = fminf(fmaxf(x - w * 0.5f, 0.f), 1.f);
                float xmx = fminf(fmaxf(x + w * 0.5f, 0.f), 1.f);
                float ymn = fminf(fmaxf(y - hh * 0.5f, 0.f), 1.f);
                float ymx = fminf(fmaxf(y + hh * 0.5f, 0.f), 1.f);
                float* o = cand + ((size_t)b * KPRE + pos) * 4;
                o[0] = xmn; o[1] = xmx; o[2] = ymn; o[3] = ymx;
            }
        }
    }
}

// ===== Kernel 2: upper-triangle suppression bit matrix ======================
__global__ void k_mask(const float* __restrict__ cand, u64* __restrict__ mask) {
#pragma clang fp contract(off)
    const int b = blockIdx.y;
    const int c = blockIdx.x;       // row chunk of 64
    __shared__ float4 sb4[KPRE];    // 64 KB
    __shared__ float sar[KPRE];     // 16 KB areas
    {
        const float4* c4 = (const float4*)(cand + (size_t)b * KPRE * 4);
        for (int k = threadIdx.x; k < KPRE; k += blockDim.x) {
            float4 v = c4[k];
            sb4[k] = v;
            sar[k] = (v.y - v.x) * (v.w - v.z);
        }
    }
    __syncthreads();
    for (int task = threadIdx.x; task < 64 * NWORDS; task += blockDim.x) {
        const int ri = task & 63;   // lane -> row, word uniform per wave
        const int w = task >> 6;
        const int i = (c << 6) + ri;
        if (i >= KPRE) continue;
        u64 bits = 0ull;
        if (w >= c) {
            float4 bi = sb4[i];
            float ai = sar[i];
            const int j0 = w << 6;
            const int jlim = (j0 + 64 <= KPRE) ? 64 : (KPRE - j0);
            int jj = (w == c) ? ri + 1 : 0;
            for (; jj < jlim; ++jj) {
                float4 bj = sb4[j0 + jj];
                float iw = fminf(bi.y, bj.y) - fmaxf(bi.x, bj.x);
                iw = fmaxf(iw, 0.0f);
                float ih = fminf(bi.w, bj.w) - fmaxf(bi.z, bj.z);
                ih = fmaxf(ih, 0.0f);
                float inter = iw * ih;
                float aj = sar[j0 + jj];
                if (inter > 0.69f * fmaxf(ai, aj)) {
                    float uni = ai + aj - inter;
                    float iou = inter / fmaxf(uni, 1e-8f);
                    if (iou > 0.7f) bits |= (1ull << jj);
                }
            }
        }
        mask[((size_t)b * KPRE + i) * WPR + w] = bits;
    }
}

// ===== Kernel 3: greedy NMS — wave-parallel peeling per chunk ================
__device__ __forceinline__ void gl_lds16(const void* g, void* l) {
    __builtin_amdgcn_global_load_lds(
        (const __attribute__((address_space(1))) void*)g,
        (__attribute__((address_space(3))) void*)l, 16, 0, 0);
}
__device__ __forceinline__ u64 readlane64(u64 v, int l) {
    unsigned lo = (unsigned)__builtin_amdgcn_readlane((int)(unsigned)v, l);
    unsigned hi = (unsigned)__builtin_amdgcn_readlane((int)(unsigned)(v >> 32), l);
    return ((u64)hi << 32) | lo;
}
#define WAITVM0   asm volatile("s_waitcnt vmcnt(0)" ::: "memory")
#define WAITVM16  asm volatile("s_waitcnt vmcnt(16)" ::: "memory")
#define WAITVM32  asm volatile("s_waitcnt vmcnt(32)" ::: "memory")
#define SCHEDBAR  __builtin_amdgcn_sched_barrier(0)

__global__ __launch_bounds__(64) void k_nms(const u64* __restrict__ mask,
                                            const float* __restrict__ cand,
                                            const unsigned* __restrict__ meta,
                                            float* __restrict__ out) {
    const int b = blockIdx.x;
    const int lane = threadIdx.x;
    const int M = (int)meta[16 + b];
    const u64* mrow = mask + (size_t)b * KPRE * WPR;
    __shared__ u64 buf[3 * 4096];     // 96 KB triple buffer (row staging)
    __shared__ int sel[MAXOUT];       // 8 KB
    __shared__ u64 amlist_s[64];
    amlist_s[lane] = 0ull;

    u64 rem = 0ull;                   // lane l owns suppression word l
    int cnt = 0;
    const int nchunks = (M + 63) >> 6;

    auto pf_n = [&](int cc) -> int {
        if (cc >= nchunks) return 0;
        int nrows = KPRE - (cc << 6); if (nrows > 64) nrows = 64;
        return nrows >> 1;             // 1 KB (2 rows) per instruction
    };
    auto prefetch = [&](int cc) {
        int n = pf_n(cc);
        if (!n) return;
        const char* gsrc = (const char*)(mrow + ((size_t)(cc << 6)) * WPR) + lane * 16;
        char* ldst = (char*)buf + (size_t)(cc % 3) * 32768;
        for (int k = 0; k < n; ++k) gl_lds16(gsrc + k * 1024, ldst + k * 1024);
    };
    auto waitpend = [&](int n) {
        if (n == 32) { WAITVM32; } else if (n == 16) { WAITVM16; } else { WAITVM0; }
    };

    if (nchunks > 0) {
        prefetch(0);
        prefetch(1);
        for (int c = 0; c < nchunks; ++c) {
            waitpend(pf_n(c + 1));    // pf(c) landed; pf(c+1) stays in flight
            SCHEDBAR;
            const u64* bufc = buf + (size_t)(c % 3) * 4096;

            // diag block: lane holds its row's word c (one conflicted read/chunk)
            u64 x = bufc[((size_t)lane << 6) + c];
            // 64x64 bit transpose across lanes -> incoming-edge words
#define TSTAGE(S, MM)                                                         \
            { u64 y = (u64)__shfl_xor((unsigned long long)x, S);              \
              x = (lane & S) ? ((x & ((MM) << S)) | ((y & ((MM) << S)) >> S)) \
                             : ((x & (MM)) | ((y & (MM)) << S)); }
            TSTAGE(32, 0x00000000FFFFFFFFull)
            TSTAGE(16, 0x0000FFFF0000FFFFull)
            TSTAGE(8,  0x00FF00FF00FF00FFull)
            TSTAGE(4,  0x0F0F0F0F0F0F0F0Full)
            TSTAGE(2,  0x3333333333333333ull)
            TSTAGE(1,  0x5555555555555555ull)
#undef TSTAGE
            const u64 inT = x;        // lane j: bit i set iff mask[j0+i][j0+j], i<j

            u64 cur = readlane64(rem, c);
            int nrow = M - (c << 6);
            u64 live = ~cur;
            if (nrow < 64) live &= (1ull << nrow) - 1ull;

            // Kahn peeling: accept all predecessor-free live rows per pass
            u64 am = 0ull;
            while (live) {
                u64 pred = __ballot((inT & live) != 0ull);
                u64 acc = live & ~pred;
                u64 sup = __ballot((inT & acc) != 0ull);
                am |= acc;
                live &= ~(acc | sup);
            }

            int pc = __builtin_popcountll(am);
            if (cnt + pc >= MAXOUT) {     // truncate to lowest-index accepts
                int drop = cnt + pc - MAXOUT;
                for (int t = 0; t < drop; ++t)
                    am &= ~(0x8000000000000000ull >> __builtin_clzll(am));
                if (lane == 0) amlist_s[c] = am;
                cnt = MAXOUT;
                break;
            }
            cnt += pc;
            if (lane == 0) amlist_s[c] = am;
            if (c + 1 >= nchunks) break;

            // fold accepted rows' full mask words into rem
            if (am) {
                u64 a0 = 0, a1 = 0, a2 = 0, a3 = 0;
#pragma unroll
                for (int k = 0; k < 64; k += 4) {
                    u64 m0 = 0ull - ((am >> (k + 0)) & 1ull);
                    u64 m1 = 0ull - ((am >> (k + 1)) & 1ull);
                    u64 m2 = 0ull - ((am >> (k + 2)) & 1ull);
                    u64 m3 = 0ull - ((am >> (k + 3)) & 1ull);
                    a0 |= bufc[((k + 0) << 6) + lane] & m0;
                    a1 |= bufc[((k + 1) << 6) + lane] & m1;
                    a2 |= bufc[((k + 2) << 6) + lane] & m2;
                    a3 |= bufc[((k + 3) << 6) + lane] & m3;
                }
                rem |= (a0 | a1) | (a2 | a3);
            }
            prefetch(c + 2);
        }
        WAITVM0;   // in-flight gl_lds must not outlive LDS reuse / wave exit
    }

    __syncthreads();
    // expand amlist -> sel (wave-parallel, order-preserving)
    u64 myam = amlist_s[lane];
    int inc = __builtin_popcountll(myam);
    int scan = inc;
#pragma unroll
    for (int d = 1; d < 64; d <<= 1) {
        int t = __shfl_up(scan, d);
        if (lane >= d) scan += t;
    }
    int pos = scan - inc;
    while (myam) {
        int r = __builtin_ctzll(myam);
        myam &= myam - 1;
        sel[pos++] = (lane << 6) + r;
    }
    __syncthreads();

    const float4* c4 = (const float4*)(cand + (size_t)b * KPRE * 4);
    float4* o4 = (float4*)(out + (size_t)b * MAXOUT * 4);
    for (int r = lane; r < MAXOUT; r += 64) {
        float4 v = make_float4(0.0f, 0.0f, 0.0f, 0.0f);
        if (r < cnt) v = c4[sel[r]];
        o4[r] = v;
    }
}

// ---------------- launch ------------------------------------------------------
extern "C" void kernel_launch(void* const* d_in, const int* in_sizes, int n_in,
                              void* d_out, int out_size, void* d_ws, size_t ws_size,
                              hipStream_t stream) {
    const float* score   = (const float*)d_in[0];
    const float* delta   = (const float*)d_in[1];
    const float* anchors = (const float*)d_in[2];
    float* out = (float*)d_out;

    uint8_t* w8 = (uint8_t*)d_ws;
    unsigned* meta = (unsigned*)(w8 + 262144);            // cut[8] | P[8] | M[8]
    float* cand = (float*)(w8 + 532608);                  // 8 x 4000 x 4 f32
    u64* mask = (u64*)(w8 + 1044608);                     // 8 x 4000 x 64 u64

    k_front<<<NB, 1024, 0, stream>>>(score, delta, anchors, cand, meta);
    k_mask<<<dim3((KPRE + 63) / 64, NB), 256, 0, stream>>>(cand, mask);
    k_nms<<<NB, 64, 0, stream>>>(mask, cand, meta, out);
}

// Round 8
// 194.356 us; speedup vs baseline: 1.7373x; 1.3582x over previous
//
#include <hip/hip_runtime.h>
#include <stdint.h>

#define NB 8
#define NH 96
#define NW_ 96
#define NA 9
#define NANCH (NH * NW_ * NA)   // 82944
#define KPRE 4000
#define MAXOUT 2000
#define KEYCAP 4224             // >= KPRE + max expected cut-bucket size
#define WPR 64                  // mask row stride in u64 words (63 used + 1 pad)
#define NWORDS 63               // ceil(4000/64)

typedef unsigned long long u64;

// ===== Kernel 1: fused front-end (hist + scan + cut + collect + rank + decode)
__global__ __launch_bounds__(1024) void k_front(const float* __restrict__ score,
                                                const float* __restrict__ delta,
                                                const float* __restrict__ anchors,
                                                float* __restrict__ cand,
                                                unsigned* __restrict__ meta) {
#pragma clang fp contract(off)
    const int b = blockIdx.x;
    const int tid = threadIdx.x;
    const int lane = tid & 63, wid = tid >> 6;
    __shared__ unsigned h[4096];       // 16 KB histogram
    __shared__ unsigned sstart[4096];  // 16 KB bucket start offsets
    __shared__ unsigned bc[4096];      // 16 KB bucket counters
    __shared__ u64 keysl[KEYCAP];      // 33.8 KB candidate keys
    __shared__ unsigned wsum[16], wabove[16];
    __shared__ unsigned s_cut, s_P, s_M;

    for (int k = tid; k < 4096; k += 1024) { h[k] = 0u; bc[k] = 0u; }
    __syncthreads();

    const float* sc = score + (size_t)b * NANCH;
    for (int i = tid; i < NANCH; i += 1024) {
        float v = sc[i];
        if (v > 0.5f) atomicAdd(&h[(__float_as_uint(v) >> 11) & 4095u], 1u);
    }
    __syncthreads();

    // suffix scan: thread t owns buckets [4t, 4t+4)
    unsigned l0 = h[tid * 4 + 0], l1 = h[tid * 4 + 1], l2 = h[tid * 4 + 2], l3 = h[tid * 4 + 3];
    unsigned s3 = l3, s2 = l2 + s3, s1 = l1 + s2, s0 = l0 + s1;
    unsigned incl = s0;
#pragma unroll
    for (int d = 1; d < 64; d <<= 1) {
        unsigned t = __shfl_down(incl, d);
        if (lane + d < 64) incl += t;
    }
    if (lane == 0) wsum[wid] = incl;
    __syncthreads();
    if (tid < 16) {
        unsigned a = 0;
        for (int w = tid + 1; w < 16; ++w) a += wsum[w];
        wabove[tid] = a;
    }
    __syncthreads();
    unsigned ta = (incl - s0) + wabove[wid];   // suffix strictly above this thread's buckets
    unsigned f0 = s0 + ta, f1 = s1 + ta, f2 = s2 + ta, f3 = s3 + ta, f4 = ta;
    sstart[tid * 4 + 0] = f1; sstart[tid * 4 + 1] = f2;
    sstart[tid * 4 + 2] = f3; sstart[tid * 4 + 3] = f4;
    if (tid == 0) {
        unsigned total = f0;
        unsigned P = total < KEYCAP ? total : KEYCAP;
        s_cut = 0u; s_P = P; s_M = P < KPRE ? P : KPRE;
    }
    __syncthreads();
    {
        unsigned fa[5] = {f0, f1, f2, f3, f4};
#pragma unroll
        for (int k = 0; k < 4; ++k) {
            if (fa[k] >= (unsigned)KPRE && fa[k + 1] < (unsigned)KPRE) {
                unsigned P = fa[k] < KEYCAP ? fa[k] : KEYCAP;
                s_cut = (unsigned)(tid * 4 + k); s_P = P; s_M = (unsigned)KPRE;
            }
        }
    }
    __syncthreads();
    const unsigned cut = s_cut; const int P = (int)s_P; const int M = (int)s_M;
    if (tid == 0) meta[16 + b] = (unsigned)M;

    // collect into LDS key buffer (bucketed scatter)
    for (int i = tid; i < NANCH; i += 1024) {
        float v = sc[i];
        if (v > 0.5f) {
            unsigned bits = __float_as_uint(v);
            unsigned bucket = (bits >> 11) & 4095u;
            if (bucket >= cut) {
                unsigned pos = sstart[bucket] + atomicAdd(&bc[bucket], 1u);
                if (pos < (unsigned)KEYCAP)
                    keysl[pos] = ((u64)bits << 32) | (unsigned)(~(unsigned)i);
            }
        }
    }
    __syncthreads();

    // rank within bucket -> exact sorted position; decode box there
    for (int s = tid; s < KEYCAP; s += 1024) {
        if (s >= M && s < KPRE) {
            float4* c4 = (float4*)(cand + (size_t)b * KPRE * 4);
            c4[s] = make_float4(0.f, 0.f, 0.f, 0.f);
        }
        if (s < P) {
            u64 key = keysl[s];
            unsigned bucket = (unsigned)(key >> 43) & 4095u;
            int base = (int)sstart[bucket];
            int end = (bucket > 0) ? (int)sstart[bucket - 1] : P;
            if (end > P) end = P;
            int rank = 0;
            for (int t = base; t < end; ++t) rank += (keysl[t] > key) ? 1 : 0;
            int pos = base + rank;
            if (pos < KPRE) {
                int n = (int)(~(unsigned)(key & 0xFFFFFFFFull));
                float4 t4 = *(const float4*)(delta + ((size_t)b * NANCH + n) * 4);
                float4 a4 = *(const float4*)(anchors + (size_t)n * 4);
                float xa = (a4.x + a4.y) * 0.5f;
                float ya = (a4.z + a4.w) * 0.5f;
                float wa = a4.y - a4.x;
                float ha = a4.w - a4.z;
                float x = t4.x * wa + xa;
                float y = t4.y * ha + ya;
                float w = expf(t4.z) * wa;
                float hh = expf(t4.w) * ha;
                float xmn = fminf(fmaxf(x - w * 0.5f, 0.f), 1.f);
                float xmx = fminf(fmaxf(x + w * 0.5f, 0.f), 1.f);
                float ymn = fminf(fmaxf(y - hh * 0.5f, 0.f), 1.f);
                float ymx = fminf(fmaxf(y + hh * 0.5f, 0.f), 1.f);
                float* o = cand + ((size_t)b * KPRE + pos) * 4;
                o[0] = xmn; o[1] = xmx; o[2] = ymn; o[3] = ymx;
            }
        }
    }
}

// ===== Kernel 2: upper-triangle suppression bit matrix (hi-occupancy) ========
__global__ __launch_bounds__(1024) void k_mask(const float* __restrict__ cand,
                                               u64* __restrict__ mask) {
#pragma clang fp contract(off)
    const int b = blockIdx.y;
    const int c = blockIdx.x;       // row chunk of 64
    __shared__ float4 sb4[KPRE];    // 64 KB
    __shared__ float sar[KPRE];     // 16 KB areas
    const int j0c = c << 6;         // this block never touches j < j0c
    {
        const float4* c4 = (const float4*)(cand + (size_t)b * KPRE * 4);
        for (int k = j0c + threadIdx.x; k < KPRE; k += blockDim.x) {
            float4 v = c4[k];
            sb4[k] = v;
            sar[k] = (v.y - v.x) * (v.w - v.z);
        }
    }
    __syncthreads();
    const int nw = NWORDS - c;      // active words for this block
    for (int task = threadIdx.x; task < (nw << 6); task += blockDim.x) {
        const int ri = task & 63;   // lane -> row (consecutive), word uniform per wave
        const int w = c + (task >> 6);
        const int i = j0c + ri;
        if (i >= KPRE) continue;
        u64 bits = 0ull;
        float4 bi = sb4[i];
        float ai = sar[i];
        const int j0 = w << 6;
        const int jlim = (j0 + 64 <= KPRE) ? 64 : (KPRE - j0);
        int jj = (w == c) ? ri + 1 : 0;
#pragma unroll 4
        for (; jj < jlim; ++jj) {
            float4 bj = sb4[j0 + jj];
            float iw = fminf(bi.y, bj.y) - fmaxf(bi.x, bj.x);
            iw = fmaxf(iw, 0.0f);
            float ih = fminf(bi.w, bj.w) - fmaxf(bi.z, bj.z);
            ih = fmaxf(ih, 0.0f);
            float inter = iw * ih;
            float aj = sar[j0 + jj];
            if (inter > 0.69f * fmaxf(ai, aj)) {
                float uni = ai + aj - inter;
                float iou = inter / fmaxf(uni, 1e-8f);
                if (iou > 0.7f) bits |= (1ull << jj);
            }
        }
        mask[((size_t)b * KPRE + i) * WPR + w] = bits;
    }
}

// ===== Kernel 3: greedy NMS — wave-parallel peeling per chunk ================
__device__ __forceinline__ void gl_lds16(const void* g, void* l) {
    __builtin_amdgcn_global_load_lds(
        (const __attribute__((address_space(1))) void*)g,
        (__attribute__((address_space(3))) void*)l, 16, 0, 0);
}
__device__ __forceinline__ u64 readlane64(u64 v, int l) {
    unsigned lo = (unsigned)__builtin_amdgcn_readlane((int)(unsigned)v, l);
    unsigned hi = (unsigned)__builtin_amdgcn_readlane((int)(unsigned)(v >> 32), l);
    return ((u64)hi << 32) | lo;
}
#define WAITVM0   asm volatile("s_waitcnt vmcnt(0)" ::: "memory")
#define WAITVM16  asm volatile("s_waitcnt vmcnt(16)" ::: "memory")
#define WAITVM32  asm volatile("s_waitcnt vmcnt(32)" ::: "memory")
#define SCHEDBAR  __builtin_amdgcn_sched_barrier(0)

__global__ __launch_bounds__(64) void k_nms(const u64* __restrict__ mask,
                                            const float* __restrict__ cand,
                                            const unsigned* __restrict__ meta,
                                            float* __restrict__ out) {
    const int b = blockIdx.x;
    const int lane = threadIdx.x;
    const int M = (int)meta[16 + b];
    const u64* mrow = mask + (size_t)b * KPRE * WPR;
    __shared__ u64 buf[3 * 4096];     // 96 KB triple buffer (row staging)
    __shared__ int sel[MAXOUT];       // 8 KB
    __shared__ u64 amlist_s[64];
    amlist_s[lane] = 0ull;

    u64 rem = 0ull;                   // lane l owns suppression word l
    int cnt = 0;
    const int nchunks = (M + 63) >> 6;

    auto pf_n = [&](int cc) -> int {
        if (cc >= nchunks) return 0;
        int nrows = KPRE - (cc << 6); if (nrows > 64) nrows = 64;
        return nrows >> 1;             // 1 KB (2 rows) per instruction
    };
    auto prefetch = [&](int cc) {
        int n = pf_n(cc);
        if (!n) return;
        const char* gsrc = (const char*)(mrow + ((size_t)(cc << 6)) * WPR) + lane * 16;
        char* ldst = (char*)buf + (size_t)(cc % 3) * 32768;
        for (int k = 0; k < n; ++k) gl_lds16(gsrc + k * 1024, ldst + k * 1024);
    };
    auto waitpend = [&](int n) {
        if (n == 32) { WAITVM32; } else if (n == 16) { WAITVM16; } else { WAITVM0; }
    };

    if (nchunks > 0) {
        prefetch(0);
        prefetch(1);
        for (int c = 0; c < nchunks; ++c) {
            waitpend(pf_n(c + 1));    // pf(c) landed; pf(c+1) stays in flight
            SCHEDBAR;
            const u64* bufc = buf + (size_t)(c % 3) * 4096;

            // diag block: lane holds its row's word c (one conflicted read/chunk)
            u64 x = bufc[((size_t)lane << 6) + c];
            // 64x64 bit transpose across lanes -> incoming-edge words
#define TSTAGE(S, MM)                                                         \
            { u64 y = (u64)__shfl_xor((unsigned long long)x, S);              \
              x = (lane & S) ? ((x & ((MM) << S)) | ((y & ((MM) << S)) >> S)) \
                             : ((x & (MM)) | ((y & (MM)) << S)); }
            TSTAGE(32, 0x00000000FFFFFFFFull)
            TSTAGE(16, 0x0000FFFF0000FFFFull)
            TSTAGE(8,  0x00FF00FF00FF00FFull)
            TSTAGE(4,  0x0F0F0F0F0F0F0F0Full)
            TSTAGE(2,  0x3333333333333333ull)
            TSTAGE(1,  0x5555555555555555ull)
#undef TSTAGE
            const u64 inT = x;        // lane j: bit i set iff mask[j0+i][j0+j], i<j

            u64 cur = readlane64(rem, c);
            int nrow = M - (c << 6);
            u64 live = ~cur;
            if (nrow < 64) live &= (1ull << nrow) - 1ull;

            // Kahn peeling: accept all predecessor-free live rows per pass
            u64 am = 0ull;
            while (live) {
                u64 pred = __ballot((inT & live) != 0ull);
                u64 acc = live & ~pred;
                u64 sup = __ballot((inT & acc) != 0ull);
                am |= acc;
                live &= ~(acc | sup);
            }

            int pc = __builtin_popcountll(am);
            if (cnt + pc >= MAXOUT) {     // truncate to lowest-index accepts
                int drop = cnt + pc - MAXOUT;
                for (int t = 0; t < drop; ++t)
                    am &= ~(0x8000000000000000ull >> __builtin_clzll(am));
                if (lane == 0) amlist_s[c] = am;
                cnt = MAXOUT;
                break;
            }
            cnt += pc;
            if (lane == 0) amlist_s[c] = am;
            if (c + 1 >= nchunks) break;

            // fold accepted rows' full mask words into rem
            if (am) {
                u64 a0 = 0, a1 = 0, a2 = 0, a3 = 0;
#pragma unroll
                for (int k = 0; k < 64; k += 4) {
                    u64 m0 = 0ull - ((am >> (k + 0)) & 1ull);
                    u64 m1 = 0ull - ((am >> (k + 1)) & 1ull);
                    u64 m2 = 0ull - ((am >> (k + 2)) & 1ull);
                    u64 m3 = 0ull - ((am >> (k + 3)) & 1ull);
                    a0 |= bufc[((k + 0) << 6) + lane] & m0;
                    a1 |= bufc[((k + 1) << 6) + lane] & m1;
                    a2 |= bufc[((k + 2) << 6) + lane] & m2;
                    a3 |= bufc[((k + 3) << 6) + lane] & m3;
                }
                rem |= (a0 | a1) | (a2 | a3);
            }
            prefetch(c + 2);
        }
        WAITVM0;   // in-flight gl_lds must not outlive LDS reuse / wave exit
    }

    __syncthreads();
    // expand amlist -> sel (wave-parallel, order-preserving)
    u64 myam = amlist_s[lane];
    int inc = __builtin_popcountll(myam);
    int scan = inc;
#pragma unroll
    for (int d = 1; d < 64; d <<= 1) {
        int t = __shfl_up(scan, d);
        if (lane >= d) scan += t;
    }
    int pos = scan - inc;
    while (myam) {
        int r = __builtin_ctzll(myam);
        myam &= myam - 1;
        sel[pos++] = (lane << 6) + r;
    }
    __syncthreads();

    const float4* c4 = (const float4*)(cand + (size_t)b * KPRE * 4);
    float4* o4 = (float4*)(out + (size_t)b * MAXOUT * 4);
    for (int r = lane; r < MAXOUT; r += 64) {
        float4 v = make_float4(0.0f, 0.0f, 0.0f, 0.0f);
        if (r < cnt) v = c4[sel[r]];
        o4[r] = v;
    }
}

// ---------------- launch ------------------------------------------------------
extern "C" void kernel_launch(void* const* d_in, const int* in_sizes, int n_in,
                              void* d_out, int out_size, void* d_ws, size_t ws_size,
                              hipStream_t stream) {
    const float* score   = (const float*)d_in[0];
    const float* delta   = (const float*)d_in[1];
    const float* anchors = (const float*)d_in[2];
    float* out = (float*)d_out;

    uint8_t* w8 = (uint8_t*)d_ws;
    unsigned* meta = (unsigned*)(w8 + 262144);            // cut[8] | P[8] | M[8]
    float* cand = (float*)(w8 + 532608);                  // 8 x 4000 x 4 f32
    u64* mask = (u64*)(w8 + 1044608);                     // 8 x 4000 x 64 u64

    k_front<<<NB, 1024, 0, stream>>>(score, delta, anchors, cand, meta);
    k_mask<<<dim3((KPRE + 63) / 64, NB), 1024, 0, stream>>>(cand, mask);
    k_nms<<<NB, 64, 0, stream>>>(mask, cand, meta, out);
}

// Round 9
// 183.503 us; speedup vs baseline: 1.8401x; 1.0591x over previous
//
#include <hip/hip_runtime.h>
#include <stdint.h>

#define NB 8
#define NH 96
#define NW_ 96
#define NA 9
#define NANCH (NH * NW_ * NA)   // 82944
#define KPRE 4000
#define MAXOUT 2000
#define KEYCAP 4224             // >= KPRE + max expected cut-bucket size
#define WPR 64                  // mask row stride in u64 words (63 used + 1 pad)
#define NWORDS 63               // ceil(4000/64)

typedef unsigned long long u64;

// ===== Kernel 1: fused front-end (hist + scan + cut + collect + rank + decode)
__global__ __launch_bounds__(1024) void k_front(const float* __restrict__ score,
                                                const float* __restrict__ delta,
                                                const float* __restrict__ anchors,
                                                float* __restrict__ cand,
                                                unsigned* __restrict__ meta) {
#pragma clang fp contract(off)
    const int b = blockIdx.x;
    const int tid = threadIdx.x;
    const int lane = tid & 63, wid = tid >> 6;
    __shared__ unsigned h[4096];       // 16 KB histogram
    __shared__ unsigned sstart[4096];  // 16 KB bucket start offsets
    __shared__ unsigned bc[4096];      // 16 KB bucket counters
    __shared__ u64 keysl[KEYCAP];      // 33.8 KB candidate keys
    __shared__ unsigned wsum[16], wabove[16];
    __shared__ unsigned s_cut, s_P, s_M;

    for (int k = tid; k < 4096; k += 1024) { h[k] = 0u; bc[k] = 0u; }
    __syncthreads();

    const float* sc = score + (size_t)b * NANCH;
    for (int i = tid; i < NANCH; i += 1024) {
        float v = sc[i];
        if (v > 0.5f) atomicAdd(&h[(__float_as_uint(v) >> 11) & 4095u], 1u);
    }
    __syncthreads();

    // suffix scan: thread t owns buckets [4t, 4t+4)
    unsigned l0 = h[tid * 4 + 0], l1 = h[tid * 4 + 1], l2 = h[tid * 4 + 2], l3 = h[tid * 4 + 3];
    unsigned s3 = l3, s2 = l2 + s3, s1 = l1 + s2, s0 = l0 + s1;
    unsigned incl = s0;
#pragma unroll
    for (int d = 1; d < 64; d <<= 1) {
        unsigned t = __shfl_down(incl, d);
        if (lane + d < 64) incl += t;
    }
    if (lane == 0) wsum[wid] = incl;
    __syncthreads();
    if (tid < 16) {
        unsigned a = 0;
        for (int w = tid + 1; w < 16; ++w) a += wsum[w];
        wabove[tid] = a;
    }
    __syncthreads();
    unsigned ta = (incl - s0) + wabove[wid];   // suffix strictly above this thread's buckets
    unsigned f0 = s0 + ta, f1 = s1 + ta, f2 = s2 + ta, f3 = s3 + ta, f4 = ta;
    sstart[tid * 4 + 0] = f1; sstart[tid * 4 + 1] = f2;
    sstart[tid * 4 + 2] = f3; sstart[tid * 4 + 3] = f4;
    if (tid == 0) {
        unsigned total = f0;
        unsigned P = total < KEYCAP ? total : KEYCAP;
        s_cut = 0u; s_P = P; s_M = P < KPRE ? P : KPRE;
    }
    __syncthreads();
    {
        unsigned fa[5] = {f0, f1, f2, f3, f4};
#pragma unroll
        for (int k = 0; k < 4; ++k) {
            if (fa[k] >= (unsigned)KPRE && fa[k + 1] < (unsigned)KPRE) {
                unsigned P = fa[k] < KEYCAP ? fa[k] : KEYCAP;
                s_cut = (unsigned)(tid * 4 + k); s_P = P; s_M = (unsigned)KPRE;
            }
        }
    }
    __syncthreads();
    const unsigned cut = s_cut; const int P = (int)s_P; const int M = (int)s_M;
    if (tid == 0) meta[16 + b] = (unsigned)M;

    // collect into LDS key buffer (bucketed scatter)
    for (int i = tid; i < NANCH; i += 1024) {
        float v = sc[i];
        if (v > 0.5f) {
            unsigned bits = __float_as_uint(v);
            unsigned bucket = (bits >> 11) & 4095u;
            if (bucket >= cut) {
                unsigned pos = sstart[bucket] + atomicAdd(&bc[bucket], 1u);
                if (pos < (unsigned)KEYCAP)
                    keysl[pos] = ((u64)bits << 32) | (unsigned)(~(unsigned)i);
            }
        }
    }
    __syncthreads();

    // rank within bucket -> exact sorted position; decode box there
    for (int s = tid; s < KEYCAP; s += 1024) {
        if (s >= M && s < KPRE) {
            float4* c4 = (float4*)(cand + (size_t)b * KPRE * 4);
            c4[s] = make_float4(0.f, 0.f, 0.f, 0.f);
        }
        if (s < P) {
            u64 key = keysl[s];
            unsigned bucket = (unsigned)(key >> 43) & 4095u;
            int base = (int)sstart[bucket];
            int end = (bucket > 0) ? (int)sstart[bucket - 1] : P;
            if (end > P) end = P;
            int rank = 0;
            for (int t = base; t < end; ++t) rank += (keysl[t] > key) ? 1 : 0;
            int pos = base + rank;
            if (pos < KPRE) {
                int n = (int)(~(unsigned)(key & 0xFFFFFFFFull));
                float4 t4 = *(const float4*)(delta + ((size_t)b * NANCH + n) * 4);
                float4 a4 = *(const float4*)(anchors + (size_t)n * 4);
                float xa = (a4.x + a4.y) * 0.5f;
                float ya = (a4.z + a4.w) * 0.5f;
                float wa = a4.y - a4.x;
                float ha = a4.w - a4.z;
                float x = t4.x * wa + xa;
                float y = t4.y * ha + ya;
                float w = expf(t4.z) * wa;
                float hh = expf(t4.w) * ha;
                float xmn = fminf(fmaxf(x - w * 0.5f, 0.f), 1.f);
                float xmx = fminf(fmaxf(x + w * 0.5f, 0.f), 1.f);
                float ymn = fminf(fmaxf(y - hh * 0.5f, 0.f), 1.f);
                float ymx = fminf(fmaxf(y + hh * 0.5f, 0.f), 1.f);
                float* o = cand + ((size_t)b * KPRE + pos) * 4;
                o[0] = xmn; o[1] = xmx; o[2] = ymn; o[3] = ymx;
            }
        }
    }
}

// ===== Kernel 2: upper-triangle suppression bit matrix (hi-occupancy) ========
__global__ __launch_bounds__(1024) void k_mask(const float* __restrict__ cand,
                                               u64* __restrict__ mask) {
#pragma clang fp contract(off)
    const int b = blockIdx.y;
    const int c = blockIdx.x;       // row chunk of 64
    __shared__ float4 sb4[KPRE];    // 64 KB
    __shared__ float sar[KPRE];     // 16 KB areas
    const int j0c = c << 6;         // this block never touches j < j0c
    {
        const float4* c4 = (const float4*)(cand + (size_t)b * KPRE * 4);
        for (int k = j0c + threadIdx.x; k < KPRE; k += blockDim.x) {
            float4 v = c4[k];
            sb4[k] = v;
            sar[k] = (v.y - v.x) * (v.w - v.z);
        }
    }
    __syncthreads();
    const int nw = NWORDS - c;      // active words for this block
    for (int task = threadIdx.x; task < (nw << 6); task += blockDim.x) {
        const int ri = task & 63;   // lane -> row (consecutive), word uniform per wave
        const int w = c + (task >> 6);
        const int i = j0c + ri;
        if (i >= KPRE) continue;
        u64 bits = 0ull;
        float4 bi = sb4[i];
        float ai = sar[i];
        const int j0 = w << 6;
        const int jlim = (j0 + 64 <= KPRE) ? 64 : (KPRE - j0);
        int jj = (w == c) ? ri + 1 : 0;
#pragma unroll 4
        for (; jj < jlim; ++jj) {
            float4 bj = sb4[j0 + jj];
            float iw = fminf(bi.y, bj.y) - fmaxf(bi.x, bj.x);
            iw = fmaxf(iw, 0.0f);
            float ih = fminf(bi.w, bj.w) - fmaxf(bi.z, bj.z);
            ih = fmaxf(ih, 0.0f);
            float inter = iw * ih;
            float aj = sar[j0 + jj];
            if (inter > 0.69f * fmaxf(ai, aj)) {
                float uni = ai + aj - inter;
                float iou = inter / fmaxf(uni, 1e-8f);
                if (iou > 0.7f) bits |= (1ull << jj);
            }
        }
        mask[((size_t)b * KPRE + i) * WPR + w] = bits;
    }
}

// ===== Kernel 3: greedy NMS — scanner wave + folder waves ====================
__device__ __forceinline__ void gl_lds16(const void* g, void* l) {
    __builtin_amdgcn_global_load_lds(
        (const __attribute__((address_space(1))) void*)g,
        (__attribute__((address_space(3))) void*)l, 16, 0, 0);
}
#define WAITVM0   asm volatile("s_waitcnt vmcnt(0)" ::: "memory")
#define WAITVM16  asm volatile("s_waitcnt vmcnt(16)" ::: "memory")
#define WAITVM32  asm volatile("s_waitcnt vmcnt(32)" ::: "memory")
// raw barrier: LDS-drain only, NO vmcnt drain (keeps prefetch in flight)
#define BAR_RAW   do { asm volatile("s_waitcnt lgkmcnt(0)" ::: "memory"); \
                       __builtin_amdgcn_s_barrier(); } while (0)

__global__ __launch_bounds__(256) void k_nms(const u64* __restrict__ mask,
                                             const float* __restrict__ cand,
                                             const unsigned* __restrict__ meta,
                                             float* __restrict__ out) {
    const int b = blockIdx.x;
    const int tid = threadIdx.x;
    const int lane = tid & 63;
    const int wv = tid >> 6;
    const int M = (int)meta[16 + b];
    const u64* mrow = mask + (size_t)b * KPRE * WPR;
    __shared__ u64 buf[3 * 4096];     // 96 KB triple buffer (row staging)
    __shared__ u64 diagL[2][64];      // conflict-free diag double buffer
    __shared__ u64 remP[64];          // distributed suppression bitmap (word l)
    __shared__ u64 amlist_s[64];
    __shared__ int sel[MAXOUT];       // 8 KB
    __shared__ u64 s_am;
    __shared__ int s_done, s_cnt;

    if (tid < 64) { remP[tid] = 0ull; amlist_s[tid] = 0ull; }
    if (tid == 0) { s_done = 0; s_cnt = 0; s_am = 0ull; }

    const int nchunks = (M + 63) >> 6;

    auto pf_n = [&](int cc) -> int {
        if (cc >= nchunks) return 0;
        int nrows = KPRE - (cc << 6); if (nrows > 64) nrows = 64;
        return nrows >> 1;             // 1 KB (2 rows) per instruction
    };
    auto prefetch = [&](int cc) {      // scanner wave only
        int n = pf_n(cc);
        if (!n) return;
        const char* gsrc = (const char*)(mrow + ((size_t)(cc << 6)) * WPR) + lane * 16;
        char* ldst = (char*)buf + (size_t)(cc % 3) * 32768;
        for (int k = 0; k < n; ++k) gl_lds16(gsrc + k * 1024, ldst + k * 1024);
    };

    int cnt = 0;                       // scanner-local running accept count
    if (nchunks > 0) {
        if (wv == 0) {
            prefetch(0);
            prefetch(1);
            int n1 = pf_n(1);
            if (n1 == 32) { WAITVM32; } else if (n1 == 16) { WAITVM16; } else { WAITVM0; }
        }
        BAR_RAW;                       // buf(0) visible to all waves
        if (wv == 1) diagL[0][lane] = buf[((size_t)lane << 6) + 0];
        BAR_RAW;

        for (int c = 0; c < nchunks; ++c) {
            if (wv == 0) {
                // ---- serial chain: diag (pre-staged) -> transpose -> peel ----
                u64 x = diagL[c & 1][lane];
#define TSTAGE(S, MM)                                                         \
                { u64 y = (u64)__shfl_xor((unsigned long long)x, S);          \
                  x = (lane & S) ? ((x & ((MM) << S)) | ((y & ((MM) << S)) >> S)) \
                                 : ((x & (MM)) | ((y & (MM)) << S)); }
                TSTAGE(32, 0x00000000FFFFFFFFull)
                TSTAGE(16, 0x0000FFFF0000FFFFull)
                TSTAGE(8,  0x00FF00FF00FF00FFull)
                TSTAGE(4,  0x0F0F0F0F0F0F0F0Full)
                TSTAGE(2,  0x3333333333333333ull)
                TSTAGE(1,  0x5555555555555555ull)
#undef TSTAGE
                const u64 inT = x;     // lane j: bit i iff edge (j0+i)->(j0+j), i<j

                u64 curw = remP[c];    // broadcast read (folded through chunk c-1)
                int nrow = M - (c << 6);
                u64 live = ~curw;
                if (nrow < 64) live &= (1ull << nrow) - 1ull;

                u64 am = 0ull;         // Kahn peeling
                while (live) {
                    u64 pred = __ballot((inT & live) != 0ull);
                    u64 acc = live & ~pred;
                    u64 sup = __ballot((inT & acc) != 0ull);
                    am |= acc;
                    live &= ~(acc | sup);
                }
                int pc = __builtin_popcountll(am);
                int trunc = 0;
                if (cnt + pc >= MAXOUT) {      // truncate to lowest-index accepts
                    int drop = cnt + pc - MAXOUT;
                    for (int t = 0; t < drop; ++t)
                        am &= ~(0x8000000000000000ull >> __builtin_clzll(am));
                    cnt = MAXOUT; trunc = 1;
                } else {
                    cnt += pc;
                }
                if (lane == 0) {
                    amlist_s[c] = am; s_am = am; s_cnt = cnt; s_done = trunc;
                }
                WAITVM0;               // pf(c+1) fully in LDS (cross-wave via bar)
            }
            BAR_RAW;                   // bar1: am/done published, buf(c+1) ready
            if ((s_done != 0) || (c + 1 >= nchunks)) break;
            u64 am = s_am;
            if (wv == 0) {
                prefetch(c + 2);       // in flight across barriers (counted, no drain)
            } else {
                // ---- folders: fold chunk c accepts into remP (split rows) ----
                const u64* bufc = buf + (size_t)(c % 3) * 4096;
                const int k0 = (wv == 1) ? 0 : (wv == 2) ? 21 : 43;
                const int k1 = (wv == 1) ? 21 : (wv == 2) ? 43 : 64;
                u64 a0 = 0ull;
                for (int k = k0; k < k1; ++k)
                    a0 |= bufc[((size_t)k << 6) + lane] & (0ull - ((am >> k) & 1ull));
                if (a0) {
                    atomicOr((unsigned*)&remP[lane] + 0, (unsigned)a0);
                    atomicOr((unsigned*)&remP[lane] + 1, (unsigned)(a0 >> 32));
                }
                if (wv == 1)           // stage next chunk's diag (off-chain)
                    diagL[(c + 1) & 1][lane] =
                        buf[(size_t)((c + 1) % 3) * 4096 + ((size_t)lane << 6) + (c + 1)];
            }
            BAR_RAW;                   // bar2: remP/diagL complete for chunk c+1
        }
        if (wv == 0) { WAITVM0; }      // drain in-flight gl_lds before exit
    }

    __syncthreads();
    const int cntF = s_cnt;
    if (wv == 0) {
        // expand amlist -> sel (order-preserving prefix scan over chunks)
        u64 myam = amlist_s[lane];
        int inc = __builtin_popcountll(myam);
        int scan = inc;
#pragma unroll
        for (int d = 1; d < 64; d <<= 1) {
            int t = __shfl_up(scan, d);
            if (lane >= d) scan += t;
        }
        int pos = scan - inc;
        while (myam) {
            int r = __builtin_ctzll(myam);
            myam &= myam - 1;
            sel[pos++] = (lane << 6) + r;
        }
    }
    __syncthreads();

    const float4* c4 = (const float4*)(cand + (size_t)b * KPRE * 4);
    float4* o4 = (float4*)(out + (size_t)b * MAXOUT * 4);
    for (int r = tid; r < MAXOUT; r += 256) {
        float4 v = make_float4(0.0f, 0.0f, 0.0f, 0.0f);
        if (r < cntF) v = c4[sel[r]];
        o4[r] = v;
    }
}

// ---------------- launch ------------------------------------------------------
extern "C" void kernel_launch(void* const* d_in, const int* in_sizes, int n_in,
                              void* d_out, int out_size, void* d_ws, size_t ws_size,
                              hipStream_t stream) {
    const float* score   = (const float*)d_in[0];
    const float* delta   = (const float*)d_in[1];
    const float* anchors = (const float*)d_in[2];
    float* out = (float*)d_out;

    uint8_t* w8 = (uint8_t*)d_ws;
    unsigned* meta = (unsigned*)(w8 + 262144);            // cut[8] | P[8] | M[8]
    float* cand = (float*)(w8 + 532608);                  // 8 x 4000 x 4 f32
    u64* mask = (u64*)(w8 + 1044608);                     // 8 x 4000 x 64 u64

    k_front<<<NB, 1024, 0, stream>>>(score, delta, anchors, cand, meta);
    k_mask<<<dim3((KPRE + 63) / 64, NB), 1024, 0, stream>>>(cand, mask);
    k_nms<<<NB, 256, 0, stream>>>(mask, cand, meta, out);
}

// Round 11
// 161.160 us; speedup vs baseline: 2.0952x; 1.1386x over previous
//
#include <hip/hip_runtime.h>
#include <stdint.h>

#define NB 8
#define NH 96
#define NW_ 96
#define NA 9
#define NANCH (NH * NW_ * NA)   // 82944
#define KPRE 4000
#define MAXOUT 2000
#define KEYCAP 4224             // >= KPRE + max expected cut-bucket size
#define NWORDS 63               // ceil(4000/64)
#define EB_CAP 2048             // edges per (batch, target-chunk) bucket (global)

typedef unsigned long long u64;

__device__ __forceinline__ u64 readlane64(u64 v, int l) {
    unsigned lo = (unsigned)__builtin_amdgcn_readlane((int)(unsigned)v, l);
    unsigned hi = (unsigned)__builtin_amdgcn_readlane((int)(unsigned)(v >> 32), l);
    return ((u64)hi << 32) | lo;
}

// ---------------- Kernel 1: per-batch histogram of score bits ----------------
__global__ void k_hist(const float* __restrict__ score, unsigned* __restrict__ hist) {
    const int b = blockIdx.y;
    __shared__ unsigned h[4096];
    for (int i = threadIdx.x; i < 4096; i += blockDim.x) h[i] = 0u;
    __syncthreads();
    const float* s = score + (size_t)b * NANCH;
    int start = blockIdx.x * blockDim.x + threadIdx.x;
    int stride = gridDim.x * blockDim.x;
    for (int i = start; i < NANCH; i += stride) {
        float v = s[i];
        if (v > 0.5f) {
            unsigned bits = __float_as_uint(v);
            atomicAdd(&h[(bits >> 11) & 4095u], 1u);
        }
    }
    __syncthreads();
    for (int k = threadIdx.x; k < 4096; k += blockDim.x) {
        unsigned c = h[k];
        if (c) atomicAdd(&hist[b * 4096 + k], c);
    }
}

// ------- Kernel 2: one wave/batch suffix-scan -> starts, cut, P, M ------------
__global__ __launch_bounds__(64) void k_cut(unsigned* __restrict__ hist,
                                            unsigned* __restrict__ start,
                                            unsigned* __restrict__ meta) {
    const int b = blockIdx.x;
    const int lane = threadIdx.x;
    const int base = b * 4096 + lane * 64;
    unsigned v[64];
#pragma unroll
    for (int k = 0; k < 64; ++k) { v[k] = hist[base + k]; }
#pragma unroll
    for (int k = 0; k < 64; ++k) { hist[base + k] = 0u; }   // becomes bcnt
#pragma unroll
    for (int k = 62; k >= 0; --k) v[k] += v[k + 1];
    unsigned tot = v[0];
    unsigned incl = tot;
#pragma unroll
    for (int d = 1; d < 64; d <<= 1) {
        unsigned t = __shfl_down(incl, d);
        if (lane + d < 64) incl += t;
    }
    unsigned sfx_above = incl - tot;          // sum over lanes > lane
    unsigned total = __shfl(incl, 0);
#pragma unroll
    for (int k = 0; k < 63; ++k) start[base + k] = v[k + 1] + sfx_above;
    start[base + 63] = sfx_above;
    if (lane == 0) {
        unsigned P = total < KEYCAP ? total : KEYCAP;
        meta[b] = 0u;
        meta[8 + b] = P;
        meta[16 + b] = P < KPRE ? P : KPRE;
    }
#pragma unroll
    for (int k = 0; k < 64; ++k) {
        unsigned sfxk = v[k] + sfx_above;
        unsigned nxt = (k < 63) ? (v[k + 1] + sfx_above) : sfx_above;
        if (sfxk >= (unsigned)KPRE && nxt < (unsigned)KPRE) {
            unsigned P = sfxk < KEYCAP ? sfxk : KEYCAP;
            meta[b] = (unsigned)(lane * 64 + k);
            meta[8 + b] = P;
            meta[16 + b] = (unsigned)KPRE;
        }
    }
}

// ---------------- Kernel 3: bucketed scatter of candidate keys ---------------
__global__ void k_collect(const float* __restrict__ score, const unsigned* __restrict__ meta,
                          const unsigned* __restrict__ start, unsigned* __restrict__ bcnt,
                          u64* __restrict__ keys) {
    const int b = blockIdx.y;
    const unsigned cut = meta[b];
    const float* sc = score + (size_t)b * NANCH;
    int i0 = blockIdx.x * blockDim.x + threadIdx.x;
    int stride = gridDim.x * blockDim.x;
    for (int i = i0; i < NANCH; i += stride) {
        float v = sc[i];
        if (v > 0.5f) {
            unsigned bits = __float_as_uint(v);
            unsigned bucket = (bits >> 11) & 4095u;
            if (bucket >= cut) {
                unsigned pos = start[b * 4096 + bucket] + atomicAdd(&bcnt[b * 4096 + bucket], 1u);
                if (pos < (unsigned)KEYCAP)
                    keys[(size_t)b * KEYCAP + pos] =
                        ((u64)bits << 32) | (unsigned)(~(unsigned)i);
            }
        }
    }
}

// -------- Kernel 4: rank within bucket (exact sort position) + decode --------
__global__ void k_rank_decode(const u64* __restrict__ keys,
                              const unsigned* __restrict__ start,
                              const unsigned* __restrict__ meta,
                              const float* __restrict__ delta,
                              const float* __restrict__ anchors,
                              float* __restrict__ cand) {
#pragma clang fp contract(off)
    const int b = blockIdx.y;
    const int s = blockIdx.x * blockDim.x + threadIdx.x;
    const int P = (int)meta[8 + b];
    const int M = (int)meta[16 + b];
    if (s >= M && s < KPRE) {
        float4* c4 = (float4*)(cand + (size_t)b * KPRE * 4);
        c4[s] = make_float4(0.f, 0.f, 0.f, 0.f);
    }
    if (s >= P) return;
    const u64* kb = keys + (size_t)b * KEYCAP;
    u64 key = kb[s];
    unsigned bucket = (unsigned)(key >> 43) & 4095u;
    int base = (int)start[b * 4096 + bucket];
    int end = (bucket > 0) ? (int)start[b * 4096 + bucket - 1] : P;
    if (end > P) end = P;
    int rank = 0;
    for (int t = base; t < end; ++t) rank += (kb[t] > key) ? 1 : 0;
    int pos = base + rank;
    if (pos >= KPRE) return;
    int n = (int)(~(unsigned)(key & 0xFFFFFFFFull));
    float4 t4 = *(const float4*)(delta + ((size_t)b * NANCH + n) * 4);
    float4 a4 = *(const float4*)(anchors + (size_t)n * 4);
    float xa = (a4.x + a4.y) * 0.5f;
    float ya = (a4.z + a4.w) * 0.5f;
    float wa = a4.y - a4.x;
    float ha = a4.w - a4.z;
    float x = t4.x * wa + xa;
    float y = t4.y * ha + ya;
    float w = expf(t4.z) * wa;
    float h = expf(t4.w) * ha;
    float xmn = fminf(fmaxf(x - w * 0.5f, 0.f), 1.f);
    float xmx = fminf(fmaxf(x + w * 0.5f, 0.f), 1.f);
    float ymn = fminf(fmaxf(y - h * 0.5f, 0.f), 1.f);
    float ymx = fminf(fmaxf(y + h * 0.5f, 0.f), 1.f);
    float* o = cand + ((size_t)b * KPRE + pos) * 4;
    o[0] = xmn; o[1] = xmx; o[2] = ymn; o[3] = ymx;
}

// ===== Kernel 5: sparse edge extraction (IoU>0.7 pairs, bucketed by j-chunk) =
__global__ __launch_bounds__(1024) void k_geo(const float* __restrict__ cand,
                                              unsigned* __restrict__ ecnt,
                                              unsigned* __restrict__ ebuf) {
#pragma clang fp contract(off)
    const int b = blockIdx.y;
    const int c = blockIdx.x;       // row chunk of 64
    __shared__ float4 sb4[KPRE];    // 64 KB
    __shared__ float sar[KPRE];     // 16 KB areas
    const int j0c = c << 6;
    {
        const float4* c4 = (const float4*)(cand + (size_t)b * KPRE * 4);
        for (int k = j0c + threadIdx.x; k < KPRE; k += blockDim.x) {
            float4 v = c4[k];
            sb4[k] = v;
            sar[k] = (v.y - v.x) * (v.w - v.z);
        }
    }
    __syncthreads();
    const int nw = NWORDS - c;
    for (int task = threadIdx.x; task < (nw << 6); task += blockDim.x) {
        const int ri = task & 63;
        const int w = c + (task >> 6);
        const int i = j0c + ri;
        if (i >= KPRE) continue;
        float4 bi = sb4[i];
        float ai = sar[i];
        const int j0 = w << 6;
        const int jlim = (j0 + 64 <= KPRE) ? 64 : (KPRE - j0);
        int jj = (w == c) ? ri + 1 : 0;
        for (; jj < jlim; ++jj) {
            float4 bj = sb4[j0 + jj];
            float iw = fminf(bi.y, bj.y) - fmaxf(bi.x, bj.x);
            if (iw > 0.0f) {
                float ih = fminf(bi.w, bj.w) - fmaxf(bi.z, bj.z);
                if (ih > 0.0f) {
                    float inter = iw * ih;
                    float aj = sar[j0 + jj];
                    if (inter > 0.69f * fmaxf(ai, aj)) {
                        float uni = ai + aj - inter;
                        float iou = inter / fmaxf(uni, 1e-8f);
                        if (iou > 0.7f) {
                            unsigned slot = atomicAdd(&ecnt[b * 64 + w], 1u);
                            if (slot < (unsigned)EB_CAP)
                                ebuf[(((size_t)(b * 64 + w)) << 11) + slot] =
                                    ((unsigned)i << 6) | (unsigned)jj;
                        }
                    }
                }
            }
        }
    }
}

// ===== Kernel 6: greedy NMS — single wave, register-only hot loop ============
__global__ __launch_bounds__(64) void k_nms(const float* __restrict__ cand,
                                            const unsigned* __restrict__ ecnt,
                                            const unsigned* __restrict__ ebuf,
                                            const unsigned* __restrict__ meta,
                                            float* __restrict__ out) {
#pragma clang fp contract(off)
    const int b = blockIdx.x;
    const int lane = threadIdx.x;
    const int M = (int)meta[16 + b];
    const int nchunks = (M + 63) >> 6;

    __shared__ float4 bx[KPRE];      // 64 KB (slow path + output gather)
    __shared__ float sar[KPRE];      // 16 KB
    __shared__ int sel[MAXOUT];      // 8 KB

    const float4* c4 = (const float4*)(cand + (size_t)b * KPRE * 4);
    for (int k = lane; k < KPRE; k += 64) {
        float4 v = c4[k];
        bx[k] = v;
        sar[k] = (v.y - v.x) * (v.w - v.z);
    }

    auto iougt = [&](float4 A, float aA, float4 Bq, float aB) -> bool {
#pragma clang fp contract(off)
        float iw = fminf(A.y, Bq.y) - fmaxf(A.x, Bq.x);
        iw = fmaxf(iw, 0.0f);
        float ih = fminf(A.w, Bq.w) - fmaxf(A.z, Bq.z);
        ih = fmaxf(ih, 0.0f);
        float inter = iw * ih;
        float uni = aA + aB - inter;
        return inter / fmaxf(uni, 1e-8f) > 0.7f;
    };

    unsigned ncnt = ecnt[b * 64 + lane];   // lane c holds bucket c's edge count
    u64 accReg = 0ull;                     // lane l = accepted bits of chunk l
    int cnt = 0;

    for (int c = 0; c < nchunks; ++c) {
        const unsigned n = (unsigned)__builtin_amdgcn_readlane((int)ncnt, c);
        u64 inT = 0ull;    // per-lane j: intra incoming-edge bits
        u64 inc0 = 0ull;   // uniform: rows suppressed by earlier-chunk accepts
        if (n != 0u && n <= (unsigned)EB_CAP) {
            const unsigned* bb = ebuf + (((size_t)(b * 64 + c)) << 11);
            for (unsigned g = 0; g < n; g += 64u) {
                unsigned eidx = g + (unsigned)lane;
                unsigned ed = (eidx < n) ? bb[eidx] : 0u;   // lane e = edge g+e
                unsigned lim = (n - g < 64u) ? (n - g) : 64u;
                for (unsigned e = 0; e < lim; ++e) {
                    unsigned edu = (unsigned)__builtin_amdgcn_readlane((int)ed, (int)e);
                    int sr = (int)(edu >> 6);       // absolute source row
                    int jj = (int)(edu & 63u);      // target row within chunk c
                    int sc = sr >> 6;
                    if (sc == c) {
                        if (lane == jj) inT |= 1ull << (sr & 63);
                    } else {
                        u64 aw = readlane64(accReg, sc);
                        if ((aw >> (sr & 63)) & 1ull) inc0 |= 1ull << jj;
                    }
                }
            }
        } else if (n > (unsigned)EB_CAP) {
            // bucket overflow (not expected on this data): exact recompute
            int r = (c << 6) + lane;
            bool valid = r < M;
            float4 bq = valid ? bx[r] : make_float4(0.f, 0.f, 0.f, 0.f);
            float aq = valid ? sar[r] : 0.f;
            for (int i2 = 0; i2 < 64; ++i2) {
                if (valid && i2 < lane) {
                    int ri = (c << 6) + i2;
                    if (iougt(bx[ri], sar[ri], bq, aq)) inT |= 1ull << i2;
                }
            }
            bool supb = false;
            for (int cc = 0; cc < c; ++cc) {
                u64 aw = readlane64(accReg, cc);
                while (aw) {
                    int rb = __builtin_ctzll(aw);
                    aw &= aw - 1;
                    int ia = (cc << 6) + rb;
                    if (valid && iougt(bx[ia], sar[ia], bq, aq)) supb = true;
                }
            }
            inc0 = __ballot(supb);
        }

        int nrow = M - (c << 6);
        u64 live = ~inc0;
        if (nrow < 64) live &= (1ull << nrow) - 1ull;

        // Kahn peeling (verified r7-r9): accept all predecessor-free per pass
        u64 am = 0ull;
        while (live) {
            u64 pred = __ballot((inT & live) != 0ull);
            u64 acc = live & ~pred;
            u64 sup = __ballot((inT & acc) != 0ull);
            am |= acc;
            live &= ~(acc | sup);
        }

        int pc = __builtin_popcountll(am);
        if (cnt + pc >= MAXOUT) {          // truncate to lowest-index accepts
            int drop = cnt + pc - MAXOUT;
            for (int t = 0; t < drop; ++t)
                am &= ~(0x8000000000000000ull >> __builtin_clzll(am));
            cnt = MAXOUT;
            if (lane == c) accReg |= am;
            break;
        }
        cnt += pc;
        if (lane == c) accReg |= am;
    }

    // expand accReg (lane = chunk word) -> sel, order-preserving
    int inc = __builtin_popcountll(accReg);
    int scan = inc;
#pragma unroll
    for (int d = 1; d < 64; d <<= 1) {
        int t = __shfl_up(scan, d);
        if (lane >= d) scan += t;
    }
    int pos = scan - inc;
    u64 t2 = accReg;
    while (t2) {
        int r = __builtin_ctzll(t2);
        t2 &= t2 - 1;
        sel[pos++] = (lane << 6) + r;
    }

    float4* o4 = (float4*)(out + (size_t)b * MAXOUT * 4);
    for (int r = lane; r < MAXOUT; r += 64) {
        float4 v = make_float4(0.0f, 0.0f, 0.0f, 0.0f);
        if (r < cnt) v = bx[sel[r]];
        o4[r] = v;
    }
}

// ---------------- launch ------------------------------------------------------
extern "C" void kernel_launch(void* const* d_in, const int* in_sizes, int n_in,
                              void* d_out, int out_size, void* d_ws, size_t ws_size,
                              hipStream_t stream) {
    const float* score   = (const float*)d_in[0];
    const float* delta   = (const float*)d_in[1];
    const float* anchors = (const float*)d_in[2];
    float* out = (float*)d_out;

    uint8_t* w8 = (uint8_t*)d_ws;
    unsigned* hist = (unsigned*)(w8 + 0);                 // 8 x 4096 u32 (then bcnt)
    unsigned* start = (unsigned*)(w8 + 131072);           // 8 x 4096 u32
    unsigned* meta = (unsigned*)(w8 + 262144);            // cut[8] | P[8] | M[8]
    u64* keys = (u64*)(w8 + 262272);                      // 8 x 4224 u64
    float* cand = (float*)(w8 + 532608);                  // 8 x 4000 x 4 f32
    unsigned* ecnt = (unsigned*)(w8 + 1044608);           // 8 x 64 u32
    unsigned* ebuf = (unsigned*)(w8 + 1048576);           // 8 x 64 x 2048 u32 (4 MB)

    hipMemsetAsync(hist, 0, 8 * 4096 * sizeof(unsigned), stream);
    hipMemsetAsync(ecnt, 0, 8 * 64 * sizeof(unsigned), stream);
    k_hist<<<dim3(16, NB), 256, 0, stream>>>(score, hist);
    k_cut<<<NB, 64, 0, stream>>>(hist, start, meta);
    k_collect<<<dim3(32, NB), 256, 0, stream>>>(score, meta, start, hist /*bcnt*/, keys);
    k_rank_decode<<<dim3((KEYCAP + 255) / 256, NB), 256, 0, stream>>>(keys, start, meta,
                                                                      delta, anchors, cand);
    k_geo<<<dim3(NWORDS, NB), 1024, 0, stream>>>(cand, ecnt, ebuf);
    k_nms<<<NB, 64, 0, stream>>>(cand, ecnt, ebuf, meta, out);
}

// Round 12
// 150.642 us; speedup vs baseline: 2.2415x; 1.0698x over previous
//
#include <hip/hip_runtime.h>
#include <stdint.h>

#define NB 8
#define NH 96
#define NW_ 96
#define NA 9
#define NANCH (NH * NW_ * NA)   // 82944
#define KPRE 4000
#define MAXOUT 2000
#define KEYCAP 4224             // >= KPRE + max expected cut-bucket size
#define NWORDS 63               // ceil(4000/64)
#define NTASKS 2016             // sum_{c=0}^{62} (63-c)
#define EB_CAP 2048             // edges per (batch, target-chunk) bucket (global)

typedef unsigned long long u64;

__device__ __forceinline__ u64 readlane64(u64 v, int l) {
    unsigned lo = (unsigned)__builtin_amdgcn_readlane((int)(unsigned)v, l);
    unsigned hi = (unsigned)__builtin_amdgcn_readlane((int)(unsigned)(v >> 32), l);
    return ((u64)hi << 32) | lo;
}
__device__ __forceinline__ float readlane_f(float v, int l) {
    return __uint_as_float((unsigned)__builtin_amdgcn_readlane((int)__float_as_uint(v), l));
}

// ---------------- Kernel 1: per-batch histogram of score bits ----------------
__global__ void k_hist(const float* __restrict__ score, unsigned* __restrict__ hist) {
    const int b = blockIdx.y;
    __shared__ unsigned h[4096];
    for (int i = threadIdx.x; i < 4096; i += blockDim.x) h[i] = 0u;
    __syncthreads();
    const float* s = score + (size_t)b * NANCH;
    int start = blockIdx.x * blockDim.x + threadIdx.x;
    int stride = gridDim.x * blockDim.x;
    for (int i = start; i < NANCH; i += stride) {
        float v = s[i];
        if (v > 0.5f) {
            unsigned bits = __float_as_uint(v);
            atomicAdd(&h[(bits >> 11) & 4095u], 1u);
        }
    }
    __syncthreads();
    for (int k = threadIdx.x; k < 4096; k += blockDim.x) {
        unsigned c = h[k];
        if (c) atomicAdd(&hist[b * 4096 + k], c);
    }
}

// ------- Kernel 2: one wave/batch suffix-scan -> starts, cut, P, M ------------
__global__ __launch_bounds__(64) void k_cut(unsigned* __restrict__ hist,
                                            unsigned* __restrict__ start,
                                            unsigned* __restrict__ meta) {
    const int b = blockIdx.x;
    const int lane = threadIdx.x;
    const int base = b * 4096 + lane * 64;
    unsigned v[64];
#pragma unroll
    for (int k = 0; k < 64; ++k) { v[k] = hist[base + k]; }
#pragma unroll
    for (int k = 0; k < 64; ++k) { hist[base + k] = 0u; }   // becomes bcnt
#pragma unroll
    for (int k = 62; k >= 0; --k) v[k] += v[k + 1];
    unsigned tot = v[0];
    unsigned incl = tot;
#pragma unroll
    for (int d = 1; d < 64; d <<= 1) {
        unsigned t = __shfl_down(incl, d);
        if (lane + d < 64) incl += t;
    }
    unsigned sfx_above = incl - tot;          // sum over lanes > lane
    unsigned total = __shfl(incl, 0);
#pragma unroll
    for (int k = 0; k < 63; ++k) start[base + k] = v[k + 1] + sfx_above;
    start[base + 63] = sfx_above;
    if (lane == 0) {
        unsigned P = total < KEYCAP ? total : KEYCAP;
        meta[b] = 0u;
        meta[8 + b] = P;
        meta[16 + b] = P < KPRE ? P : KPRE;
    }
#pragma unroll
    for (int k = 0; k < 64; ++k) {
        unsigned sfxk = v[k] + sfx_above;
        unsigned nxt = (k < 63) ? (v[k + 1] + sfx_above) : sfx_above;
        if (sfxk >= (unsigned)KPRE && nxt < (unsigned)KPRE) {
            unsigned P = sfxk < KEYCAP ? sfxk : KEYCAP;
            meta[b] = (unsigned)(lane * 64 + k);
            meta[8 + b] = P;
            meta[16 + b] = (unsigned)KPRE;
        }
    }
}

// ---------------- Kernel 3: bucketed scatter of candidate keys ---------------
__global__ void k_collect(const float* __restrict__ score, const unsigned* __restrict__ meta,
                          const unsigned* __restrict__ start, unsigned* __restrict__ bcnt,
                          u64* __restrict__ keys) {
    const int b = blockIdx.y;
    const unsigned cut = meta[b];
    const float* sc = score + (size_t)b * NANCH;
    int i0 = blockIdx.x * blockDim.x + threadIdx.x;
    int stride = gridDim.x * blockDim.x;
    for (int i = i0; i < NANCH; i += stride) {
        float v = sc[i];
        if (v > 0.5f) {
            unsigned bits = __float_as_uint(v);
            unsigned bucket = (bits >> 11) & 4095u;
            if (bucket >= cut) {
                unsigned pos = start[b * 4096 + bucket] + atomicAdd(&bcnt[b * 4096 + bucket], 1u);
                if (pos < (unsigned)KEYCAP)
                    keys[(size_t)b * KEYCAP + pos] =
                        ((u64)bits << 32) | (unsigned)(~(unsigned)i);
            }
        }
    }
}

// -------- Kernel 4: rank within bucket (exact sort position) + decode --------
__global__ void k_rank_decode(const u64* __restrict__ keys,
                              const unsigned* __restrict__ start,
                              const unsigned* __restrict__ meta,
                              const float* __restrict__ delta,
                              const float* __restrict__ anchors,
                              float* __restrict__ cand) {
#pragma clang fp contract(off)
    const int b = blockIdx.y;
    const int s = blockIdx.x * blockDim.x + threadIdx.x;
    const int P = (int)meta[8 + b];
    const int M = (int)meta[16 + b];
    if (s >= M && s < KPRE) {
        float4* c4 = (float4*)(cand + (size_t)b * KPRE * 4);
        c4[s] = make_float4(0.f, 0.f, 0.f, 0.f);
    }
    if (s >= P) return;
    const u64* kb = keys + (size_t)b * KEYCAP;
    u64 key = kb[s];
    unsigned bucket = (unsigned)(key >> 43) & 4095u;
    int base = (int)start[b * 4096 + bucket];
    int end = (bucket > 0) ? (int)start[b * 4096 + bucket - 1] : P;
    if (end > P) end = P;
    int rank = 0;
    for (int t = base; t < end; ++t) rank += (kb[t] > key) ? 1 : 0;
    int pos = base + rank;
    if (pos >= KPRE) return;
    int n = (int)(~(unsigned)(key & 0xFFFFFFFFull));
    float4 t4 = *(const float4*)(delta + ((size_t)b * NANCH + n) * 4);
    float4 a4 = *(const float4*)(anchors + (size_t)n * 4);
    float xa = (a4.x + a4.y) * 0.5f;
    float ya = (a4.z + a4.w) * 0.5f;
    float wa = a4.y - a4.x;
    float ha = a4.w - a4.z;
    float x = t4.x * wa + xa;
    float y = t4.y * ha + ya;
    float w = expf(t4.z) * wa;
    float h = expf(t4.w) * ha;
    float xmn = fminf(fmaxf(x - w * 0.5f, 0.f), 1.f);
    float xmx = fminf(fmaxf(x + w * 0.5f, 0.f), 1.f);
    float ymn = fminf(fmaxf(y - h * 0.5f, 0.f), 1.f);
    float ymx = fminf(fmaxf(y + h * 0.5f, 0.f), 1.f);
    float* o = cand + ((size_t)b * KPRE + pos) * 4;
    o[0] = xmn; o[1] = xmx; o[2] = ymn; o[3] = ymx;
}

// ===== Kernel 5: sparse edge extraction — register tiles, zero LDS ===========
// One wave per (c,w) upper-triangle tile: lane j holds box w*64+j; the 64
// i-boxes (chunk c) are lane-distributed and broadcast via v_readlane.
__global__ __launch_bounds__(64) void k_geo(const float* __restrict__ cand,
                                            unsigned* __restrict__ ecnt,
                                            unsigned* __restrict__ ebuf) {
#pragma clang fp contract(off)
    const int b = blockIdx.y;
    const int lane = threadIdx.x;
    // decode flat task -> (c, w), w in [c, 63)
    int t = blockIdx.x;
    int c = 0;
    while (true) { int n = NWORDS - c; if (t < n) break; t -= n; ++c; }
    const int w = c + t;

    const float4* c4 = (const float4*)(cand + (size_t)b * KPRE * 4);
    const int jq = (w << 6) + lane;
    const bool jvalid = jq < KPRE;
    float4 bq = c4[jvalid ? jq : (KPRE - 1)];
    float aq = (bq.y - bq.x) * (bq.w - bq.z);
    const int iq = (c << 6) + lane;
    float4 bc_ = c4[(iq < KPRE) ? iq : (KPRE - 1)];
    float4 ar4;  // pack area with box to reduce readlanes? keep separate scalar
    float ac_ = (bc_.y - bc_.x) * (bc_.w - bc_.z);
    (void)ar4;

    const int ilim = (KPRE - (c << 6)) < 64 ? (KPRE - (c << 6)) : 64;
    unsigned* cl = &ecnt[b * 64 + w];
    unsigned* bb = ebuf + (((size_t)(b * 64 + w)) << 11);

    for (int i = 0; i < ilim; ++i) {
        float bix = readlane_f(bc_.x, i);
        float biy = readlane_f(bc_.y, i);
        float biz = readlane_f(bc_.z, i);
        float biw = readlane_f(bc_.w, i);
        float ai  = readlane_f(ac_, i);
        float iw = fminf(biy, bq.y) - fmaxf(bix, bq.x);
        float ih = fminf(biw, bq.w) - fmaxf(biz, bq.z);
        bool ok = jvalid && (iw > 0.0f) && (ih > 0.0f);
        if (w == c) ok = ok && (lane > i);
        float inter = iw * ih;
        ok = ok && (inter > 0.69f * fmaxf(ai, aq));
        if (__any(ok)) {
            float uni = ai + aq - inter;
            bool hit = ok && (inter / fmaxf(uni, 1e-8f) > 0.7f);
            u64 word = __ballot(hit);
            if (word != 0ull && lane == 0) {
                int pc = __builtin_popcountll(word);
                unsigned slot = atomicAdd(cl, (unsigned)pc);
                unsigned iabs = (unsigned)((c << 6) + i);
                while (word) {
                    int jj = __builtin_ctzll(word);
                    word &= word - 1;
                    if (slot < (unsigned)EB_CAP) bb[slot] = (iabs << 6) | (unsigned)jj;
                    ++slot;
                }
            }
        }
    }
}

// ===== Kernel 6: greedy NMS — single wave, register-only hot loop ============
__global__ __launch_bounds__(64) void k_nms(const float* __restrict__ cand,
                                            const unsigned* __restrict__ ecnt,
                                            const unsigned* __restrict__ ebuf,
                                            const unsigned* __restrict__ meta,
                                            float* __restrict__ out) {
#pragma clang fp contract(off)
    const int b = blockIdx.x;
    const int lane = threadIdx.x;
    const int M = (int)meta[16 + b];
    const int nchunks = (M + 63) >> 6;

    __shared__ float4 bx[KPRE];      // 64 KB (slow path + output gather)
    __shared__ float sar[KPRE];      // 16 KB
    __shared__ int sel[MAXOUT];      // 8 KB

    const float4* c4 = (const float4*)(cand + (size_t)b * KPRE * 4);
    for (int k = lane; k < KPRE; k += 64) {
        float4 v = c4[k];
        bx[k] = v;
        sar[k] = (v.y - v.x) * (v.w - v.z);
    }

    auto iougt = [&](float4 A, float aA, float4 Bq, float aB) -> bool {
#pragma clang fp contract(off)
        float iw = fminf(A.y, Bq.y) - fmaxf(A.x, Bq.x);
        iw = fmaxf(iw, 0.0f);
        float ih = fminf(A.w, Bq.w) - fmaxf(A.z, Bq.z);
        ih = fmaxf(ih, 0.0f);
        float inter = iw * ih;
        float uni = aA + aB - inter;
        return inter / fmaxf(uni, 1e-8f) > 0.7f;
    };

    unsigned ncnt = ecnt[b * 64 + lane];   // lane c holds bucket c's edge count
    u64 accReg = 0ull;                     // lane l = accepted bits of chunk l
    int cnt = 0;

    for (int c = 0; c < nchunks; ++c) {
        const unsigned n = (unsigned)__builtin_amdgcn_readlane((int)ncnt, c);
        u64 inT = 0ull;    // per-lane j: intra incoming-edge bits
        u64 inc0 = 0ull;   // uniform: rows suppressed by earlier-chunk accepts
        if (n != 0u && n <= (unsigned)EB_CAP) {
            const unsigned* bb = ebuf + (((size_t)(b * 64 + c)) << 11);
            for (unsigned g = 0; g < n; g += 64u) {
                unsigned eidx = g + (unsigned)lane;
                unsigned ed = (eidx < n) ? bb[eidx] : 0u;   // lane e = edge g+e
                unsigned lim = (n - g < 64u) ? (n - g) : 64u;
                for (unsigned e = 0; e < lim; ++e) {
                    unsigned edu = (unsigned)__builtin_amdgcn_readlane((int)ed, (int)e);
                    int sr = (int)(edu >> 6);       // absolute source row
                    int jj = (int)(edu & 63u);      // target row within chunk c
                    int sc = sr >> 6;
                    if (sc == c) {
                        if (lane == jj) inT |= 1ull << (sr & 63);
                    } else {
                        u64 aw = readlane64(accReg, sc);
                        if ((aw >> (sr & 63)) & 1ull) inc0 |= 1ull << jj;
                    }
                }
            }
        } else if (n > (unsigned)EB_CAP) {
            // bucket overflow (not expected on this data): exact recompute
            int r = (c << 6) + lane;
            bool valid = r < M;
            float4 bq = valid ? bx[r] : make_float4(0.f, 0.f, 0.f, 0.f);
            float aq = valid ? sar[r] : 0.f;
            for (int i2 = 0; i2 < 64; ++i2) {
                if (valid && i2 < lane) {
                    int ri = (c << 6) + i2;
                    if (iougt(bx[ri], sar[ri], bq, aq)) inT |= 1ull << i2;
                }
            }
            bool supb = false;
            for (int cc = 0; cc < c; ++cc) {
                u64 aw = readlane64(accReg, cc);
                while (aw) {
                    int rb = __builtin_ctzll(aw);
                    aw &= aw - 1;
                    int ia = (cc << 6) + rb;
                    if (valid && iougt(bx[ia], sar[ia], bq, aq)) supb = true;
                }
            }
            inc0 = __ballot(supb);
        }

        int nrow = M - (c << 6);
        u64 live = ~inc0;
        if (nrow < 64) live &= (1ull << nrow) - 1ull;

        // Kahn peeling (verified r7-r11): accept all predecessor-free per pass
        u64 am = 0ull;
        while (live) {
            u64 pred = __ballot((inT & live) != 0ull);
            u64 acc = live & ~pred;
            u64 sup = __ballot((inT & acc) != 0ull);
            am |= acc;
            live &= ~(acc | sup);
        }

        int pc = __builtin_popcountll(am);
        if (cnt + pc >= MAXOUT) {          // truncate to lowest-index accepts
            int drop = cnt + pc - MAXOUT;
            for (int t = 0; t < drop; ++t)
                am &= ~(0x8000000000000000ull >> __builtin_clzll(am));
            cnt = MAXOUT;
            if (lane == c) accReg |= am;
            break;
        }
        cnt += pc;
        if (lane == c) accReg |= am;
    }

    // expand accReg (lane = chunk word) -> sel, order-preserving
    int inc = __builtin_popcountll(accReg);
    int scan = inc;
#pragma unroll
    for (int d = 1; d < 64; d <<= 1) {
        int t = __shfl_up(scan, d);
        if (lane >= d) scan += t;
    }
    int pos = scan - inc;
    u64 t2 = accReg;
    while (t2) {
        int r = __builtin_ctzll(t2);
        t2 &= t2 - 1;
        sel[pos++] = (lane << 6) + r;
    }

    float4* o4 = (float4*)(out + (size_t)b * MAXOUT * 4);
    for (int r = lane; r < MAXOUT; r += 64) {
        float4 v = make_float4(0.0f, 0.0f, 0.0f, 0.0f);
        if (r < cnt) v = bx[sel[r]];
        o4[r] = v;
    }
}

// ---------------- launch ------------------------------------------------------
extern "C" void kernel_launch(void* const* d_in, const int* in_sizes, int n_in,
                              void* d_out, int out_size, void* d_ws, size_t ws_size,
                              hipStream_t stream) {
    const float* score   = (const float*)d_in[0];
    const float* delta   = (const float*)d_in[1];
    const float* anchors = (const float*)d_in[2];
    float* out = (float*)d_out;

    uint8_t* w8 = (uint8_t*)d_ws;
    unsigned* hist = (unsigned*)(w8 + 0);                 // 8 x 4096 u32 (then bcnt)
    unsigned* start = (unsigned*)(w8 + 131072);           // 8 x 4096 u32
    unsigned* meta = (unsigned*)(w8 + 262144);            // cut[8] | P[8] | M[8]
    u64* keys = (u64*)(w8 + 262272);                      // 8 x 4224 u64
    float* cand = (float*)(w8 + 532608);                  // 8 x 4000 x 4 f32
    unsigned* ecnt = (unsigned*)(w8 + 1044608);           // 8 x 64 u32
    unsigned* ebuf = (unsigned*)(w8 + 1048576);           // 8 x 64 x 2048 u32 (4 MB)

    hipMemsetAsync(hist, 0, 8 * 4096 * sizeof(unsigned), stream);
    hipMemsetAsync(ecnt, 0, 8 * 64 * sizeof(unsigned), stream);
    k_hist<<<dim3(16, NB), 256, 0, stream>>>(score, hist);
    k_cut<<<NB, 64, 0, stream>>>(hist, start, meta);
    k_collect<<<dim3(32, NB), 256, 0, stream>>>(score, meta, start, hist /*bcnt*/, keys);
    k_rank_decode<<<dim3((KEYCAP + 255) / 256, NB), 256, 0, stream>>>(keys, start, meta,
                                                                      delta, anchors, cand);
    k_geo<<<dim3(NTASKS, NB), 64, 0, stream>>>(cand, ecnt, ebuf);
    k_nms<<<NB, 64, 0, stream>>>(cand, ecnt, ebuf, meta, out);
}

// Round 13
// 136.527 us; speedup vs baseline: 2.4732x; 1.1034x over previous
//
#include <hip/hip_runtime.h>
#include <stdint.h>

#define NB 8
#define NH 96
#define NW_ 96
#define NA 9
#define NANCH (NH * NW_ * NA)   // 82944
#define KPRE 4000
#define MAXOUT 2000
#define KEYCAP 4224             // >= KPRE + max expected cut-bucket size
#define NWORDS 63               // ceil(4000/64)
#define NTASKS 2016             // sum_{c=0}^{62} (63-c)
#define EB_CAP 2048             // edges per (batch, target-chunk) bucket (global)

typedef unsigned long long u64;

__device__ __forceinline__ u64 readlane64(u64 v, int l) {
    unsigned lo = (unsigned)__builtin_amdgcn_readlane((int)(unsigned)v, l);
    unsigned hi = (unsigned)__builtin_amdgcn_readlane((int)(unsigned)(v >> 32), l);
    return ((u64)hi << 32) | lo;
}
__device__ __forceinline__ float readlane_f(float v, int l) {
    return __uint_as_float((unsigned)__builtin_amdgcn_readlane((int)__float_as_uint(v), l));
}

// ---------------- Kernel 1: per-batch histogram of score bits ----------------
__global__ void k_hist(const float* __restrict__ score, unsigned* __restrict__ hist) {
    const int b = blockIdx.y;
    __shared__ unsigned h[4096];
    for (int i = threadIdx.x; i < 4096; i += blockDim.x) h[i] = 0u;
    __syncthreads();
    const float* s = score + (size_t)b * NANCH;
    int start = blockIdx.x * blockDim.x + threadIdx.x;
    int stride = gridDim.x * blockDim.x;
    for (int i = start; i < NANCH; i += stride) {
        float v = s[i];
        if (v > 0.5f) {
            unsigned bits = __float_as_uint(v);
            atomicAdd(&h[(bits >> 11) & 4095u], 1u);
        }
    }
    __syncthreads();
    for (int k = threadIdx.x; k < 4096; k += blockDim.x) {
        unsigned c = h[k];
        if (c) atomicAdd(&hist[b * 4096 + k], c);
    }
}

// ------- Kernel 2: one wave/batch suffix-scan -> starts, cut, P, M ------------
__global__ __launch_bounds__(64) void k_cut(unsigned* __restrict__ hist,
                                            unsigned* __restrict__ start,
                                            unsigned* __restrict__ meta) {
    const int b = blockIdx.x;
    const int lane = threadIdx.x;
    const int base = b * 4096 + lane * 64;
    unsigned v[64];
#pragma unroll
    for (int k = 0; k < 64; ++k) { v[k] = hist[base + k]; }
#pragma unroll
    for (int k = 0; k < 64; ++k) { hist[base + k] = 0u; }   // becomes bcnt
#pragma unroll
    for (int k = 62; k >= 0; --k) v[k] += v[k + 1];
    unsigned tot = v[0];
    unsigned incl = tot;
#pragma unroll
    for (int d = 1; d < 64; d <<= 1) {
        unsigned t = __shfl_down(incl, d);
        if (lane + d < 64) incl += t;
    }
    unsigned sfx_above = incl - tot;          // sum over lanes > lane
    unsigned total = __shfl(incl, 0);
#pragma unroll
    for (int k = 0; k < 63; ++k) start[base + k] = v[k + 1] + sfx_above;
    start[base + 63] = sfx_above;
    if (lane == 0) {
        unsigned P = total < KEYCAP ? total : KEYCAP;
        meta[b] = 0u;
        meta[8 + b] = P;
        meta[16 + b] = P < KPRE ? P : KPRE;
    }
#pragma unroll
    for (int k = 0; k < 64; ++k) {
        unsigned sfxk = v[k] + sfx_above;
        unsigned nxt = (k < 63) ? (v[k + 1] + sfx_above) : sfx_above;
        if (sfxk >= (unsigned)KPRE && nxt < (unsigned)KPRE) {
            unsigned P = sfxk < KEYCAP ? sfxk : KEYCAP;
            meta[b] = (unsigned)(lane * 64 + k);
            meta[8 + b] = P;
            meta[16 + b] = (unsigned)KPRE;
        }
    }
}

// ---------------- Kernel 3: bucketed scatter of candidate keys ---------------
__global__ void k_collect(const float* __restrict__ score, const unsigned* __restrict__ meta,
                          const unsigned* __restrict__ start, unsigned* __restrict__ bcnt,
                          u64* __restrict__ keys) {
    const int b = blockIdx.y;
    const unsigned cut = meta[b];
    const float* sc = score + (size_t)b * NANCH;
    int i0 = blockIdx.x * blockDim.x + threadIdx.x;
    int stride = gridDim.x * blockDim.x;
    for (int i = i0; i < NANCH; i += stride) {
        float v = sc[i];
        if (v > 0.5f) {
            unsigned bits = __float_as_uint(v);
            unsigned bucket = (bits >> 11) & 4095u;
            if (bucket >= cut) {
                unsigned pos = start[b * 4096 + bucket] + atomicAdd(&bcnt[b * 4096 + bucket], 1u);
                if (pos < (unsigned)KEYCAP)
                    keys[(size_t)b * KEYCAP + pos] =
                        ((u64)bits << 32) | (unsigned)(~(unsigned)i);
            }
        }
    }
}

// -------- Kernel 4: rank within bucket (exact sort position) + decode --------
__global__ void k_rank_decode(const u64* __restrict__ keys,
                              const unsigned* __restrict__ start,
                              const unsigned* __restrict__ meta,
                              const float* __restrict__ delta,
                              const float* __restrict__ anchors,
                              float* __restrict__ cand) {
#pragma clang fp contract(off)
    const int b = blockIdx.y;
    const int s = blockIdx.x * blockDim.x + threadIdx.x;
    const int P = (int)meta[8 + b];
    const int M = (int)meta[16 + b];
    if (s >= M && s < KPRE) {
        float4* c4 = (float4*)(cand + (size_t)b * KPRE * 4);
        c4[s] = make_float4(0.f, 0.f, 0.f, 0.f);
    }
    if (s >= P) return;
    const u64* kb = keys + (size_t)b * KEYCAP;
    u64 key = kb[s];
    unsigned bucket = (unsigned)(key >> 43) & 4095u;
    int base = (int)start[b * 4096 + bucket];
    int end = (bucket > 0) ? (int)start[b * 4096 + bucket - 1] : P;
    if (end > P) end = P;
    int rank = 0;
    for (int t = base; t < end; ++t) rank += (kb[t] > key) ? 1 : 0;
    int pos = base + rank;
    if (pos >= KPRE) return;
    int n = (int)(~(unsigned)(key & 0xFFFFFFFFull));
    float4 t4 = *(const float4*)(delta + ((size_t)b * NANCH + n) * 4);
    float4 a4 = *(const float4*)(anchors + (size_t)n * 4);
    float xa = (a4.x + a4.y) * 0.5f;
    float ya = (a4.z + a4.w) * 0.5f;
    float wa = a4.y - a4.x;
    float ha = a4.w - a4.z;
    float x = t4.x * wa + xa;
    float y = t4.y * ha + ya;
    float w = expf(t4.z) * wa;
    float h = expf(t4.w) * ha;
    float xmn = fminf(fmaxf(x - w * 0.5f, 0.f), 1.f);
    float xmx = fminf(fmaxf(x + w * 0.5f, 0.f), 1.f);
    float ymn = fminf(fmaxf(y - h * 0.5f, 0.f), 1.f);
    float ymx = fminf(fmaxf(y + h * 0.5f, 0.f), 1.f);
    float* o = cand + ((size_t)b * KPRE + pos) * 4;
    o[0] = xmn; o[1] = xmx; o[2] = ymn; o[3] = ymx;
}

// ===== Kernel 5: sparse edge extraction — tight register tiles ===============
__device__ __forceinline__ void emit_edges(u64 word, unsigned* cl, unsigned* bb,
                                           unsigned iabs) {
    int pc = __builtin_popcountll(word);
    unsigned slot = atomicAdd(cl, (unsigned)pc);
    while (word) {
        int jj = __builtin_ctzll(word);
        word &= word - 1;
        if (slot < (unsigned)EB_CAP) bb[slot] = (iabs << 6) | (unsigned)jj;
        ++slot;
    }
}

__global__ __launch_bounds__(64) void k_geo(const float* __restrict__ cand,
                                            unsigned* __restrict__ ecnt,
                                            unsigned* __restrict__ ebuf) {
#pragma clang fp contract(off)
    const int b = blockIdx.y;
    const int lane = threadIdx.x;
    // decode flat task -> (c, w), w in [c, 63)
    int t = blockIdx.x;
    int c = 0;
    while (true) { int n = NWORDS - c; if (t < n) break; t -= n; ++c; }
    const int w = c + t;

    const float4* c4 = (const float4*)(cand + (size_t)b * KPRE * 4);
    const int jq = (w << 6) + lane;
    const bool jvalid = jq < KPRE;
    float4 bq = c4[jvalid ? jq : (KPRE - 1)];
    float aq = (bq.y - bq.x) * (bq.w - bq.z);
    const float aq69 = 0.69f * aq;
    const int iq0 = (c << 6);
    const int il = iq0 + lane;
    float4 bc_ = c4[(il < KPRE) ? il : (KPRE - 1)];
    float ac_ = (bc_.y - bc_.x) * (bc_.w - bc_.z);
    float ac69_ = 0.69f * ac_;

    unsigned* cl = &ecnt[b * 64 + w];
    unsigned* bb = ebuf + (((size_t)(b * 64 + w)) << 11);

    if (w > c) {
        // off-diagonal: c < 62 here, so all 64 i rows are in range
#pragma unroll 8
        for (int i = 0; i < 64; ++i) {
            float bix = readlane_f(bc_.x, i);
            float biy = readlane_f(bc_.y, i);
            float biz = readlane_f(bc_.z, i);
            float biw = readlane_f(bc_.w, i);
            float ai69 = readlane_f(ac69_, i);
            float iw = fminf(biy, bq.y) - fmaxf(bix, bq.x);
            float ih = fminf(biw, bq.w) - fmaxf(biz, bq.z);
            float wh = fminf(iw, ih);
            float inter = iw * ih;
            float thr = fmaxf(ai69, aq69);      // == 0.69*max(ai,aq) bitwise
            bool ok = jvalid & (wh > 0.0f) & (inter > thr);
            if (__any(ok)) {
                float ai = readlane_f(ac_, i);
                float uni = ai + aq - inter;
                bool hit = ok && (inter / fmaxf(uni, 1e-8f) > 0.7f);
                u64 word = __ballot(hit);
                if (word && lane == 0) emit_edges(word, cl, bb, (unsigned)(iq0 + i));
            }
        }
    } else {
        // diagonal tile (w == c): triangular, dynamic row count for c == 62
        const int ilim = (KPRE - iq0) < 64 ? (KPRE - iq0) : 64;
        for (int i = 0; i < ilim; ++i) {
            float bix = readlane_f(bc_.x, i);
            float biy = readlane_f(bc_.y, i);
            float biz = readlane_f(bc_.z, i);
            float biw = readlane_f(bc_.w, i);
            float ai69 = readlane_f(ac69_, i);
            float iw = fminf(biy, bq.y) - fmaxf(bix, bq.x);
            float ih = fminf(biw, bq.w) - fmaxf(biz, bq.z);
            float wh = fminf(iw, ih);
            float inter = iw * ih;
            float thr = fmaxf(ai69, aq69);
            bool ok = jvalid & (lane > i) & (wh > 0.0f) & (inter > thr);
            if (__any(ok)) {
                float ai = readlane_f(ac_, i);
                float uni = ai + aq - inter;
                bool hit = ok && (inter / fmaxf(uni, 1e-8f) > 0.7f);
                u64 word = __ballot(hit);
                if (word && lane == 0) emit_edges(word, cl, bb, (unsigned)(iq0 + i));
            }
        }
    }
}

// ===== Kernel 6: greedy NMS — single wave, register-only hot loop ============
__global__ __launch_bounds__(64) void k_nms(const float* __restrict__ cand,
                                            const unsigned* __restrict__ ecnt,
                                            const unsigned* __restrict__ ebuf,
                                            const unsigned* __restrict__ meta,
                                            float* __restrict__ out) {
#pragma clang fp contract(off)
    const int b = blockIdx.x;
    const int lane = threadIdx.x;
    const int M = (int)meta[16 + b];
    const int nchunks = (M + 63) >> 6;

    __shared__ float4 bx[KPRE];      // 64 KB (slow path + output gather)
    __shared__ float sar[KPRE];      // 16 KB
    __shared__ int sel[MAXOUT];      // 8 KB

    const float4* c4 = (const float4*)(cand + (size_t)b * KPRE * 4);
    for (int k = lane; k < KPRE; k += 64) {
        float4 v = c4[k];
        bx[k] = v;
        sar[k] = (v.y - v.x) * (v.w - v.z);
    }

    auto iougt = [&](float4 A, float aA, float4 Bq, float aB) -> bool {
#pragma clang fp contract(off)
        float iw = fminf(A.y, Bq.y) - fmaxf(A.x, Bq.x);
        iw = fmaxf(iw, 0.0f);
        float ih = fminf(A.w, Bq.w) - fmaxf(A.z, Bq.z);
        ih = fmaxf(ih, 0.0f);
        float inter = iw * ih;
        float uni = aA + aB - inter;
        return inter / fmaxf(uni, 1e-8f) > 0.7f;
    };

    unsigned ncnt = ecnt[b * 64 + lane];   // lane c holds bucket c's edge count
    u64 accReg = 0ull;                     // lane l = accepted bits of chunk l
    int cnt = 0;

    for (int c = 0; c < nchunks; ++c) {
        const unsigned n = (unsigned)__builtin_amdgcn_readlane((int)ncnt, c);
        u64 inT = 0ull;    // per-lane j: intra incoming-edge bits
        u64 inc0 = 0ull;   // uniform: rows suppressed by earlier-chunk accepts
        if (n != 0u && n <= (unsigned)EB_CAP) {
            const unsigned* bb = ebuf + (((size_t)(b * 64 + c)) << 11);
            for (unsigned g = 0; g < n; g += 64u) {
                unsigned eidx = g + (unsigned)lane;
                unsigned ed = (eidx < n) ? bb[eidx] : 0u;   // lane e = edge g+e
                unsigned lim = (n - g < 64u) ? (n - g) : 64u;
                for (unsigned e = 0; e < lim; ++e) {
                    unsigned edu = (unsigned)__builtin_amdgcn_readlane((int)ed, (int)e);
                    int sr = (int)(edu >> 6);       // absolute source row
                    int jj = (int)(edu & 63u);      // target row within chunk c
                    int sc = sr >> 6;
                    if (sc == c) {
                        if (lane == jj) inT |= 1ull << (sr & 63);
                    } else {
                        u64 aw = readlane64(accReg, sc);
                        if ((aw >> (sr & 63)) & 1ull) inc0 |= 1ull << jj;
                    }
                }
            }
        } else if (n > (unsigned)EB_CAP) {
            // bucket overflow (not expected on this data): exact recompute
            int r = (c << 6) + lane;
            bool valid = r < M;
            float4 bq = valid ? bx[r] : make_float4(0.f, 0.f, 0.f, 0.f);
            float aq = valid ? sar[r] : 0.f;
            for (int i2 = 0; i2 < 64; ++i2) {
                if (valid && i2 < lane) {
                    int ri = (c << 6) + i2;
                    if (iougt(bx[ri], sar[ri], bq, aq)) inT |= 1ull << i2;
                }
            }
            bool supb = false;
            for (int cc = 0; cc < c; ++cc) {
                u64 aw = readlane64(accReg, cc);
                while (aw) {
                    int rb = __builtin_ctzll(aw);
                    aw &= aw - 1;
                    int ia = (cc << 6) + rb;
                    if (valid && iougt(bx[ia], sar[ia], bq, aq)) supb = true;
                }
            }
            inc0 = __ballot(supb);
        }

        int nrow = M - (c << 6);
        u64 live = ~inc0;
        if (nrow < 64) live &= (1ull << nrow) - 1ull;

        // Kahn peeling (verified r7-r12): accept all predecessor-free per pass
        u64 am = 0ull;
        while (live) {
            u64 pred = __ballot((inT & live) != 0ull);
            u64 acc = live & ~pred;
            u64 sup = __ballot((inT & acc) != 0ull);
            am |= acc;
            live &= ~(acc | sup);
        }

        int pc = __builtin_popcountll(am);
        if (cnt + pc >= MAXOUT) {          // truncate to lowest-index accepts
            int drop = cnt + pc - MAXOUT;
            for (int t = 0; t < drop; ++t)
                am &= ~(0x8000000000000000ull >> __builtin_clzll(am));
            cnt = MAXOUT;
            if (lane == c) accReg |= am;
            break;
        }
        cnt += pc;
        if (lane == c) accReg |= am;
    }

    // expand accReg (lane = chunk word) -> sel, order-preserving
    int inc = __builtin_popcountll(accReg);
    int scan = inc;
#pragma unroll
    for (int d = 1; d < 64; d <<= 1) {
        int t = __shfl_up(scan, d);
        if (lane >= d) scan += t;
    }
    int pos = scan - inc;
    u64 t2 = accReg;
    while (t2) {
        int r = __builtin_ctzll(t2);
        t2 &= t2 - 1;
        sel[pos++] = (lane << 6) + r;
    }

    float4* o4 = (float4*)(out + (size_t)b * MAXOUT * 4);
    for (int r = lane; r < MAXOUT; r += 64) {
        float4 v = make_float4(0.0f, 0.0f, 0.0f, 0.0f);
        if (r < cnt) v = bx[sel[r]];
        o4[r] = v;
    }
}

// ---------------- launch ------------------------------------------------------
extern "C" void kernel_launch(void* const* d_in, const int* in_sizes, int n_in,
                              void* d_out, int out_size, void* d_ws, size_t ws_size,
                              hipStream_t stream) {
    const float* score   = (const float*)d_in[0];
    const float* delta   = (const float*)d_in[1];
    const float* anchors = (const float*)d_in[2];
    float* out = (float*)d_out;

    uint8_t* w8 = (uint8_t*)d_ws;
    unsigned* hist  = (unsigned*)(w8 + 0);        // 8 x 4096 u32 (then bcnt)
    unsigned* ecnt  = (unsigned*)(w8 + 131072);   // 8 x 64 u32 (adjacent: one memset)
    unsigned* start = (unsigned*)(w8 + 133120);   // 8 x 4096 u32
    unsigned* meta  = (unsigned*)(w8 + 264192);   // cut[8] | P[8] | M[8]
    u64* keys       = (u64*)(w8 + 264320);        // 8 x 4224 u64
    float* cand     = (float*)(w8 + 534656);      // 8 x 4000 x 4 f32
    unsigned* ebuf  = (unsigned*)(w8 + 1046656);  // 8 x 64 x 2048 u32 (4 MB)

    hipMemsetAsync(w8, 0, 133120, stream);        // hist + ecnt in one call
    k_hist<<<dim3(16, NB), 256, 0, stream>>>(score, hist);
    k_cut<<<NB, 64, 0, stream>>>(hist, start, meta);
    k_collect<<<dim3(32, NB), 256, 0, stream>>>(score, meta, start, hist /*bcnt*/, keys);
    k_rank_decode<<<dim3((KEYCAP + 255) / 256, NB), 256, 0, stream>>>(keys, start, meta,
                                                                      delta, anchors, cand);
    k_geo<<<dim3(NTASKS, NB), 64, 0, stream>>>(cand, ecnt, ebuf);
    k_nms<<<NB, 64, 0, stream>>>(cand, ecnt, ebuf, meta, out);
}

// Round 14
// 126.829 us; speedup vs baseline: 2.6624x; 1.0765x over previous
//
#include <hip/hip_runtime.h>
#include <stdint.h>

#define NB 8
#define NH 96
#define NW_ 96
#define NA 9
#define NANCH (NH * NW_ * NA)   // 82944
#define KPRE 4000
#define MAXOUT 2000
#define KEYCAP 4224             // >= KPRE + max expected cut-bucket size
#define NWORDS 63               // ceil(4000/64)
#define GTASKS 528              // per batch: sum_c ceil((63-c)/4)
#define EB_CAP 2048             // edges per (batch, target-chunk) bucket (global)

typedef unsigned long long u64;

__device__ __forceinline__ u64 readlane64(u64 v, int l) {
    unsigned lo = (unsigned)__builtin_amdgcn_readlane((int)(unsigned)v, l);
    unsigned hi = (unsigned)__builtin_amdgcn_readlane((int)(unsigned)(v >> 32), l);
    return ((u64)hi << 32) | lo;
}
__device__ __forceinline__ float readlane_f(float v, int l) {
    return __uint_as_float((unsigned)__builtin_amdgcn_readlane((int)__float_as_uint(v), l));
}

// ------- Kernel 1: per-batch histogram (one block/batch, direct write) -------
__global__ __launch_bounds__(1024) void k_hist(const float* __restrict__ score,
                                               unsigned* __restrict__ hist) {
    const int b = blockIdx.x;
    __shared__ unsigned h[4096];
    for (int i = threadIdx.x; i < 4096; i += 1024) h[i] = 0u;
    __syncthreads();
    const float* s = score + (size_t)b * NANCH;
    for (int i = threadIdx.x; i < NANCH; i += 1024) {
        float v = s[i];
        if (v > 0.5f) atomicAdd(&h[(__float_as_uint(v) >> 11) & 4095u], 1u);
    }
    __syncthreads();
    for (int k = threadIdx.x; k < 4096; k += 1024) hist[b * 4096 + k] = h[k];
}

// ------- Kernel 2: one wave/batch suffix-scan -> starts, cut, P, M; zero ecnt
__global__ __launch_bounds__(64) void k_cut(unsigned* __restrict__ hist,
                                            unsigned* __restrict__ start,
                                            unsigned* __restrict__ meta,
                                            unsigned* __restrict__ ecnt) {
    const int b = blockIdx.x;
    const int lane = threadIdx.x;
    const int base = b * 4096 + lane * 64;
    ecnt[b * 64 + lane] = 0u;
    unsigned v[64];
#pragma unroll
    for (int k = 0; k < 64; ++k) { v[k] = hist[base + k]; }
#pragma unroll
    for (int k = 0; k < 64; ++k) { hist[base + k] = 0u; }   // becomes bcnt
#pragma unroll
    for (int k = 62; k >= 0; --k) v[k] += v[k + 1];
    unsigned tot = v[0];
    unsigned incl = tot;
#pragma unroll
    for (int d = 1; d < 64; d <<= 1) {
        unsigned t = __shfl_down(incl, d);
        if (lane + d < 64) incl += t;
    }
    unsigned sfx_above = incl - tot;          // sum over lanes > lane
    unsigned total = __shfl(incl, 0);
#pragma unroll
    for (int k = 0; k < 63; ++k) start[base + k] = v[k + 1] + sfx_above;
    start[base + 63] = sfx_above;
    if (lane == 0) {
        unsigned P = total < KEYCAP ? total : KEYCAP;
        meta[b] = 0u;
        meta[8 + b] = P;
        meta[16 + b] = P < KPRE ? P : KPRE;
    }
#pragma unroll
    for (int k = 0; k < 64; ++k) {
        unsigned sfxk = v[k] + sfx_above;
        unsigned nxt = (k < 63) ? (v[k + 1] + sfx_above) : sfx_above;
        if (sfxk >= (unsigned)KPRE && nxt < (unsigned)KPRE) {
            unsigned P = sfxk < KEYCAP ? sfxk : KEYCAP;
            meta[b] = (unsigned)(lane * 64 + k);
            meta[8 + b] = P;
            meta[16 + b] = (unsigned)KPRE;
        }
    }
}

// ---------------- Kernel 3: bucketed scatter of candidate keys ---------------
__global__ void k_collect(const float* __restrict__ score, const unsigned* __restrict__ meta,
                          const unsigned* __restrict__ start, unsigned* __restrict__ bcnt,
                          u64* __restrict__ keys) {
    const int b = blockIdx.y;
    const unsigned cut = meta[b];
    const float* sc = score + (size_t)b * NANCH;
    int i0 = blockIdx.x * blockDim.x + threadIdx.x;
    int stride = gridDim.x * blockDim.x;
    for (int i = i0; i < NANCH; i += stride) {
        float v = sc[i];
        if (v > 0.5f) {
            unsigned bits = __float_as_uint(v);
            unsigned bucket = (bits >> 11) & 4095u;
            if (bucket >= cut) {
                unsigned pos = start[b * 4096 + bucket] + atomicAdd(&bcnt[b * 4096 + bucket], 1u);
                if (pos < (unsigned)KEYCAP)
                    keys[(size_t)b * KEYCAP + pos] =
                        ((u64)bits << 32) | (unsigned)(~(unsigned)i);
            }
        }
    }
}

// -------- Kernel 4: rank within bucket (exact sort position) + decode --------
__global__ void k_rank_decode(const u64* __restrict__ keys,
                              const unsigned* __restrict__ start,
                              const unsigned* __restrict__ meta,
                              const float* __restrict__ delta,
                              const float* __restrict__ anchors,
                              float* __restrict__ cand) {
#pragma clang fp contract(off)
    const int b = blockIdx.y;
    const int s = blockIdx.x * blockDim.x + threadIdx.x;
    const int P = (int)meta[8 + b];
    const int M = (int)meta[16 + b];
    if (s >= M && s < KPRE) {
        float4* c4 = (float4*)(cand + (size_t)b * KPRE * 4);
        c4[s] = make_float4(0.f, 0.f, 0.f, 0.f);
    }
    if (s >= P) return;
    const u64* kb = keys + (size_t)b * KEYCAP;
    u64 key = kb[s];
    unsigned bucket = (unsigned)(key >> 43) & 4095u;
    int base = (int)start[b * 4096 + bucket];
    int end = (bucket > 0) ? (int)start[b * 4096 + bucket - 1] : P;
    if (end > P) end = P;
    int rank = 0;
    for (int t = base; t < end; ++t) rank += (kb[t] > key) ? 1 : 0;
    int pos = base + rank;
    if (pos >= KPRE) return;
    int n = (int)(~(unsigned)(key & 0xFFFFFFFFull));
    float4 t4 = *(const float4*)(delta + ((size_t)b * NANCH + n) * 4);
    float4 a4 = *(const float4*)(anchors + (size_t)n * 4);
    float xa = (a4.x + a4.y) * 0.5f;
    float ya = (a4.z + a4.w) * 0.5f;
    float wa = a4.y - a4.x;
    float ha = a4.w - a4.z;
    float x = t4.x * wa + xa;
    float y = t4.y * ha + ya;
    float w = expf(t4.z) * wa;
    float h = expf(t4.w) * ha;
    float xmn = fminf(fmaxf(x - w * 0.5f, 0.f), 1.f);
    float xmx = fminf(fmaxf(x + w * 0.5f, 0.f), 1.f);
    float ymn = fminf(fmaxf(y - h * 0.5f, 0.f), 1.f);
    float ymx = fminf(fmaxf(y + h * 0.5f, 0.f), 1.f);
    float* o = cand + ((size_t)b * KPRE + pos) * 4;
    o[0] = xmn; o[1] = xmx; o[2] = ymn; o[3] = ymx;
}

// ===== Kernel 5: sparse edge extraction — 4-chunk register tiles =============
__device__ __forceinline__ void emit_edges(u64 word, unsigned* cl, unsigned* bb,
                                           unsigned iabs) {
    int pc = __builtin_popcountll(word);
    unsigned slot = atomicAdd(cl, (unsigned)pc);
    while (word) {
        int jj = __builtin_ctzll(word);
        word &= word - 1;
        if (slot < (unsigned)EB_CAP) bb[slot] = (iabs << 6) | (unsigned)jj;
        ++slot;
    }
}

__global__ __launch_bounds__(256) void k_geo(const float* __restrict__ cand,
                                             unsigned* __restrict__ ecnt,
                                             unsigned* __restrict__ ebuf) {
#pragma clang fp contract(off)
    const int b = blockIdx.y;
    const int lane = threadIdx.x & 63;
    const int wv = threadIdx.x >> 6;
    // wave-task -> (c, wbase): groups of 4 j-chunks starting at w = c
    int t = (blockIdx.x << 2) + wv;       // in [0, GTASKS)
    int c = 0;
    while (true) { int n = (NWORDS - c + 3) >> 2; if (t < n) break; t -= n; ++c; }
    const int wbase = c + (t << 2);
    const bool nd0 = (wbase != c);        // slot 0 diagonal iff wbase == c

    const float4* c4 = (const float4*)(cand + (size_t)b * KPRE * 4);
    // i-side: lane holds row iq0+lane (sentinel empty if out of range)
    const int iq0 = c << 6;
    const int il = iq0 + lane;
    float4 bi_l;
    float ai_l;
    if (il < KPRE) {
        bi_l = c4[il];
        ai_l = (bi_l.y - bi_l.x) * (bi_l.w - bi_l.z);
    } else {
        bi_l = make_float4(2.f, -1.f, 2.f, -1.f);
        ai_l = 0.f;
    }
    float ai69_l = 0.69f * ai_l;

    // j-side: 4 chunk slots (sentinel empty box for invalid)
    float4 bq0, bq1, bq2, bq3;
    float aq0, aq1, aq2, aq3, aq69_0, aq69_1, aq69_2, aq69_3;
#define LOADQ(S)                                                              \
    { int w_ = wbase + S; int jq_ = (w_ << 6) + lane;                         \
      if (w_ < NWORDS && jq_ < KPRE) {                                        \
          bq##S = c4[jq_];                                                    \
          aq##S = (bq##S.y - bq##S.x) * (bq##S.w - bq##S.z);                  \
      } else { bq##S = make_float4(2.f, -1.f, 2.f, -1.f); aq##S = 0.f; }      \
      aq69_##S = 0.69f * aq##S; }
    LOADQ(0) LOADQ(1) LOADQ(2) LOADQ(3)
#undef LOADQ

#pragma unroll 4
    for (int i = 0; i < 64; ++i) {
        float bix = readlane_f(bi_l.x, i);
        float biy = readlane_f(bi_l.y, i);
        float biz = readlane_f(bi_l.z, i);
        float biw = readlane_f(bi_l.w, i);
        float ai69 = readlane_f(ai69_l, i);
        bool ok0, ok1, ok2, ok3;
        float in0, in1, in2, in3;
#define PAIR(S, OKV, INV)                                                     \
        { float iw = fminf(biy, bq##S.y) - fmaxf(bix, bq##S.x);               \
          float ih = fminf(biw, bq##S.w) - fmaxf(biz, bq##S.z);               \
          iw = fmaxf(iw, 0.0f); ih = fmaxf(ih, 0.0f);                         \
          INV = iw * ih;                                                      \
          OKV = INV > fmaxf(ai69, aq69_##S); }
        PAIR(0, ok0, in0) PAIR(1, ok1, in1) PAIR(2, ok2, in2) PAIR(3, ok3, in3)
#undef PAIR
        ok0 = ok0 && (nd0 || lane > i);
        if (__any(ok0 | ok1 | ok2 | ok3)) {
            float ai = readlane_f(ai_l, i);
#define EMIT(S, OKV, INV)                                                     \
            if (__any(OKV)) {                                                 \
                float uni = ai + aq##S - INV;                                 \
                bool hit = OKV && (INV / fmaxf(uni, 1e-8f) > 0.7f);           \
                u64 word = __ballot(hit);                                     \
                if (word && lane == 0)                                        \
                    emit_edges(word, &ecnt[b * 64 + wbase + S],               \
                               ebuf + (((size_t)(b * 64 + wbase + S)) << 11), \
                               (unsigned)(iq0 + i));                          \
            }
            EMIT(0, ok0, in0) EMIT(1, ok1, in1) EMIT(2, ok2, in2) EMIT(3, ok3, in3)
#undef EMIT
        }
    }
}

// ===== Kernel 6: greedy NMS — single wave, register-only hot loop ============
__global__ __launch_bounds__(64) void k_nms(const float* __restrict__ cand,
                                            const unsigned* __restrict__ ecnt,
                                            const unsigned* __restrict__ ebuf,
                                            const unsigned* __restrict__ meta,
                                            float* __restrict__ out) {
#pragma clang fp contract(off)
    const int b = blockIdx.x;
    const int lane = threadIdx.x;
    const int M = (int)meta[16 + b];
    const int nchunks = (M + 63) >> 6;

    __shared__ float4 bx[KPRE];      // 64 KB (fallback only)
    __shared__ float sar[KPRE];      // 16 KB (fallback only)
    __shared__ int sel[MAXOUT];      // 8 KB

    const float4* c4 = (const float4*)(cand + (size_t)b * KPRE * 4);
    unsigned ncnt = ecnt[b * 64 + lane];   // lane c holds bucket c's edge count
    const bool fb = __any(ncnt > (unsigned)EB_CAP);
    if (fb) {
        for (int k = lane; k < KPRE; k += 64) {
            float4 v = c4[k];
            bx[k] = v;
            sar[k] = (v.y - v.x) * (v.w - v.z);
        }
    }

    auto iougt = [&](float4 A, float aA, float4 Bq, float aB) -> bool {
#pragma clang fp contract(off)
        float iw = fminf(A.y, Bq.y) - fmaxf(A.x, Bq.x);
        iw = fmaxf(iw, 0.0f);
        float ih = fminf(A.w, Bq.w) - fmaxf(A.z, Bq.z);
        ih = fmaxf(ih, 0.0f);
        float inter = iw * ih;
        float uni = aA + aB - inter;
        return inter / fmaxf(uni, 1e-8f) > 0.7f;
    };

    u64 accReg = 0ull;                     // lane l = accepted bits of chunk l
    int cnt = 0;

    for (int c = 0; c < nchunks; ++c) {
        const unsigned n = (unsigned)__builtin_amdgcn_readlane((int)ncnt, c);
        u64 inT = 0ull;    // per-lane j: intra incoming-edge bits
        u64 inc0 = 0ull;   // uniform: rows suppressed by earlier-chunk accepts
        if (n != 0u && n <= (unsigned)EB_CAP) {
            const unsigned* bb = ebuf + (((size_t)(b * 64 + c)) << 11);
            for (unsigned g = 0; g < n; g += 64u) {
                unsigned eidx = g + (unsigned)lane;
                unsigned ed = (eidx < n) ? bb[eidx] : 0u;   // lane e = edge g+e
                unsigned lim = (n - g < 64u) ? (n - g) : 64u;
                for (unsigned e = 0; e < lim; ++e) {
                    unsigned edu = (unsigned)__builtin_amdgcn_readlane((int)ed, (int)e);
                    int sr = (int)(edu >> 6);       // absolute source row
                    int jj = (int)(edu & 63u);      // target row within chunk c
                    int sc = sr >> 6;
                    if (sc == c) {
                        if (lane == jj) inT |= 1ull << (sr & 63);
                    } else {
                        u64 aw = readlane64(accReg, sc);
                        if ((aw >> (sr & 63)) & 1ull) inc0 |= 1ull << jj;
                    }
                }
            }
        } else if (n > (unsigned)EB_CAP) {
            // bucket overflow (not expected on this data): exact recompute
            int r = (c << 6) + lane;
            bool valid = r < M;
            float4 bq = valid ? bx[r] : make_float4(0.f, 0.f, 0.f, 0.f);
            float aq = valid ? sar[r] : 0.f;
            for (int i2 = 0; i2 < 64; ++i2) {
                if (valid && i2 < lane) {
                    int ri = (c << 6) + i2;
                    if (iougt(bx[ri], sar[ri], bq, aq)) inT |= 1ull << i2;
                }
            }
            bool supb = false;
            for (int cc = 0; cc < c; ++cc) {
                u64 aw = readlane64(accReg, cc);
                while (aw) {
                    int rb = __builtin_ctzll(aw);
                    aw &= aw - 1;
                    int ia = (cc << 6) + rb;
                    if (valid && iougt(bx[ia], sar[ia], bq, aq)) supb = true;
                }
            }
            inc0 = __ballot(supb);
        }

        int nrow = M - (c << 6);
        u64 live = ~inc0;
        if (nrow < 64) live &= (1ull << nrow) - 1ull;

        // Kahn peeling (verified r7-r13): accept all predecessor-free per pass
        u64 am = 0ull;
        while (live) {
            u64 pred = __ballot((inT & live) != 0ull);
            u64 acc = live & ~pred;
            u64 sup = __ballot((inT & acc) != 0ull);
            am |= acc;
            live &= ~(acc | sup);
        }

        int pc = __builtin_popcountll(am);
        if (cnt + pc >= MAXOUT) {          // truncate to lowest-index accepts
            int drop = cnt + pc - MAXOUT;
            for (int t = 0; t < drop; ++t)
                am &= ~(0x8000000000000000ull >> __builtin_clzll(am));
            cnt = MAXOUT;
            if (lane == c) accReg |= am;
            break;
        }
        cnt += pc;
        if (lane == c) accReg |= am;
    }

    // expand accReg (lane = chunk word) -> sel, order-preserving
    int inc = __builtin_popcountll(accReg);
    int scan = inc;
#pragma unroll
    for (int d = 1; d < 64; d <<= 1) {
        int t = __shfl_up(scan, d);
        if (lane >= d) scan += t;
    }
    int pos = scan - inc;
    u64 t2 = accReg;
    while (t2) {
        int r = __builtin_ctzll(t2);
        t2 &= t2 - 1;
        sel[pos++] = (lane << 6) + r;
    }

    float4* o4 = (float4*)(out + (size_t)b * MAXOUT * 4);
    if (fb) {
        for (int r = lane; r < MAXOUT; r += 64) {
            float4 v = make_float4(0.0f, 0.0f, 0.0f, 0.0f);
            if (r < cnt) v = bx[sel[r]];
            o4[r] = v;
        }
    } else {
        for (int r = lane; r < MAXOUT; r += 64) {
            float4 v = make_float4(0.0f, 0.0f, 0.0f, 0.0f);
            if (r < cnt) v = c4[sel[r]];
            o4[r] = v;
        }
    }
}

// ---------------- launch ------------------------------------------------------
extern "C" void kernel_launch(void* const* d_in, const int* in_sizes, int n_in,
                              void* d_out, int out_size, void* d_ws, size_t ws_size,
                              hipStream_t stream) {
    const float* score   = (const float*)d_in[0];
    const float* delta   = (const float*)d_in[1];
    const float* anchors = (const float*)d_in[2];
    float* out = (float*)d_out;

    uint8_t* w8 = (uint8_t*)d_ws;
    unsigned* hist  = (unsigned*)(w8 + 0);        // 8 x 4096 u32 (then bcnt)
    unsigned* ecnt  = (unsigned*)(w8 + 131072);   // 8 x 64 u32 (zeroed by k_cut)
    unsigned* start = (unsigned*)(w8 + 133120);   // 8 x 4096 u32
    unsigned* meta  = (unsigned*)(w8 + 264192);   // cut[8] | P[8] | M[8]
    u64* keys       = (u64*)(w8 + 264320);        // 8 x 4224 u64
    float* cand     = (float*)(w8 + 534656);      // 8 x 4000 x 4 f32
    unsigned* ebuf  = (unsigned*)(w8 + 1046656);  // 8 x 64 x 2048 u32 (4 MB)

    k_hist<<<NB, 1024, 0, stream>>>(score, hist);
    k_cut<<<NB, 64, 0, stream>>>(hist, start, meta, ecnt);
    k_collect<<<dim3(32, NB), 256, 0, stream>>>(score, meta, start, hist /*bcnt*/, keys);
    k_rank_decode<<<dim3((KEYCAP + 255) / 256, NB), 256, 0, stream>>>(keys, start, meta,
                                                                      delta, anchors, cand);
    k_geo<<<dim3(GTASKS / 4, NB), 256, 0, stream>>>(cand, ecnt, ebuf);
    k_nms<<<NB, 64, 0, stream>>>(cand, ecnt, ebuf, meta, out);
}